// Round 1
// baseline (3858.834 us; speedup 1.0000x reference)
//
#include <hip/hip_runtime.h>

#define S_LEN 1024
#define BB 128
#define DD 256
#define NN 1024
#define TWO_K 512   // 2*DD
#define TWO_N 2048  // 2*NN

typedef _Float16 half8 __attribute__((ext_vector_type(8)));
typedef float f32x4 __attribute__((ext_vector_type(4)));

__device__ __forceinline__ float wrap2pi(float x) {
  float r = fmodf(x, 6.283185307179586f);
  if (r < 0.f) r += 6.283185307179586f;
  return r;
}
__device__ __forceinline__ int lut_index(float th) {
  float w = wrap2pi(th);
  return ((int)floorf(w * 651.8986469044033f)) & 4095;
}

// ---------------- h recurrence (pointwise over b,d) -> X0 [CH*BB, 2*DD] f16 interleaved ----------------
__global__ __launch_bounds__(64) void k_h(const int* __restrict__ ids,
                                          const float* __restrict__ emb,
                                          float* __restrict__ hstate,
                                          _Float16* __restrict__ X0,
                                          int t0, int CH) {
  __shared__ __align__(16) float2 lut[4096];
  const int tid = threadIdx.x;
  for (int i = tid; i < 4096; i += 64) {
    float ang = 0.0015339807878856412f * (float)i;
    lut[i] = make_float2(sinf(ang), cosf(ang));
  }
  __syncthreads();
  const int b = blockIdx.x;
  const int d = blockIdx.y * 64 + tid;
  float hr, hi;
  if (t0 == 0) { hr = 0.f; hi = 0.f; }
  else { float2 h = ((const float2*)hstate)[b * DD + d]; hr = h.x; hi = h.y; }
  for (int tt = 0; tt < CH; ++tt) {
    const int t = t0 + tt;
    const int id = ids[b * S_LEN + t];
    const float w  = emb[(size_t)id * 512 + d];
    const float bv = emb[(size_t)id * 512 + 256 + d];
    const float wl = 1.f + fabsf(w);
    const float tphi = wrap2pi((float)t * 1.618033988749895f);
    const float thr = hr / wl + bv + tphi;
    const float thi = hi / wl + bv + tphi;
    const float2 a = lut[lut_index(thr)];
    const float2 c = lut[lut_index(thi)];
    hr = a.y * c.y - a.x * c.x;
    hi = a.y * c.x + a.x * c.y;
    union { unsigned int u; _Float16 h2[2]; } pk;
    pk.h2[0] = (_Float16)hr; pk.h2[1] = (_Float16)hi;
    *(((unsigned int*)(X0 + (size_t)(tt * BB + b) * TWO_K)) + d) = pk.u;
  }
  ((float2*)hstate)[b * DD + d] = make_float2(hr, hi);
}

// ---------------- rotation prefix products (f64), per (l,n) ----------------
__global__ __launch_bounds__(64) void k_rot(const float* __restrict__ omega,
                                            float2* __restrict__ C0, float2* __restrict__ D0,
                                            float2* __restrict__ D1, float2* __restrict__ C1last) {
  const int gid = blockIdx.x * 64 + threadIdx.x;  // 0..2047
  if (gid >= 2 * NN) return;
  const int l = gid >> 10, n = gid & (NN - 1);
  const float om = omega[l * NN + n];
  double pr = 1.0, pi = 0.0;
  for (int t = 0; t < S_LEN; ++t) {
    const float th = om + (float)t * 1.618033988749895f;
    const int idx = lut_index(th);
    const float ang = 0.0015339807878856412f * (float)idx;
    const float sn = sinf(ang), cn = cosf(ang);
    const double npr = pr * (double)cn - pi * (double)sn;
    const double npi = pr * (double)sn + pi * (double)cn;
    pr = npr; pi = npi;
    const double m2 = pr * pr + pi * pi;
    const float2 inv = make_float2((float)(pr / m2), (float)(-pi / m2));
    if (l == 0) {
      C0[t * NN + n] = make_float2((float)pr, (float)pi);
      D0[t * NN + n] = inv;
    } else {
      D1[t * NN + n] = inv;
    }
  }
  if (l == 1) C1last[n] = make_float2((float)pr, (float)pi);
}

// ---------------- f16 MFMA GEMM: C = A @ BT^T, optional complex rotation epilogue ----------------
// A [M,K] row-major f16, BT [N,K] row-major f16 (i.e. B transposed), C [M,N] f16.
// rot: nullptr or [M/128, N/2] float2; row-block t = blockIdx.y (BM=128=BB so each tile is one t).
__global__ __launch_bounds__(256, 2) void k_gemm(const _Float16* __restrict__ A,
                                                 const _Float16* __restrict__ BT,
                                                 _Float16* __restrict__ C,
                                                 int M, int N, int K,
                                                 const float2* __restrict__ rot) {
  __shared__ __align__(16) _Float16 As[128 * 64];
  __shared__ __align__(16) _Float16 Bs[128 * 64];
  const int tid = threadIdx.x;
  const int lane = tid & 63;
  const int wave = tid >> 6;
  const int wm = wave >> 1;
  const int wn = wave & 1;
  const int m0 = blockIdx.y * 128;
  const int n0 = blockIdx.x * 128;

  const int srow = lane >> 3;               // row within 8-row chunk
  const int schunk = (lane & 7) ^ srow;     // XOR-swizzled source 16B-chunk

  f32x4 acc[4][4] = {};

  for (int kt = 0; kt < K; kt += 64) {
#pragma unroll
    for (int j = 0; j < 4; ++j) {
      const int c = wave * 4 + j;           // chunk 0..15, covers rows c*8..c*8+7
      const int row = c * 8 + srow;
      const _Float16* srcA = A + (size_t)(m0 + row) * K + kt + schunk * 8;
      __builtin_amdgcn_global_load_lds((const __attribute__((address_space(1))) void*)srcA,
                                       (__attribute__((address_space(3))) void*)(As + c * 512), 16, 0, 0);
      const _Float16* srcB = BT + (size_t)(n0 + row) * K + kt + schunk * 8;
      __builtin_amdgcn_global_load_lds((const __attribute__((address_space(1))) void*)srcB,
                                       (__attribute__((address_space(3))) void*)(Bs + c * 512), 16, 0, 0);
    }
    __syncthreads();
#pragma unroll
    for (int ks = 0; ks < 2; ++ks) {
      half8 af[4], bf[4];
#pragma unroll
      for (int mr = 0; mr < 4; ++mr) {
        const int ar = wm * 64 + mr * 16 + (lane & 15);
        const int p = ((ks * 4) + (lane >> 4)) ^ (ar & 7);
        af[mr] = *(const half8*)(As + ar * 64 + p * 8);
      }
#pragma unroll
      for (int nr = 0; nr < 4; ++nr) {
        const int br = wn * 64 + nr * 16 + (lane & 15);
        const int p = ((ks * 4) + (lane >> 4)) ^ (br & 7);
        bf[nr] = *(const half8*)(Bs + br * 64 + p * 8);
      }
#pragma unroll
      for (int mr = 0; mr < 4; ++mr)
#pragma unroll
        for (int nr = 0; nr < 4; ++nr)
          acc[mr][nr] = __builtin_amdgcn_mfma_f32_16x16x32_f16(af[mr], bf[nr], acc[mr][nr], 0, 0, 0);
    }
    __syncthreads();
  }

  const int halfN = N >> 1;
  const int t = blockIdx.y;
#pragma unroll
  for (int mr = 0; mr < 4; ++mr)
#pragma unroll
    for (int nr = 0; nr < 4; ++nr) {
      const int col = n0 + wn * 64 + nr * 16 + (lane & 15);
      const int rbase = m0 + wm * 64 + mr * 16 + ((lane >> 4) << 2);
      float2 dr = make_float2(1.f, 0.f);
      if (rot) dr = rot[(size_t)t * halfN + (col >> 1)];
#pragma unroll
      for (int j = 0; j < 4; ++j) {
        float v = acc[mr][nr][j];
        if (rot) {
          const float pv = __shfl_xor(v, 1);
          v = (lane & 1) ? (dr.x * v + dr.y * pv) : (dr.x * v - dr.y * pv);
        }
        C[(size_t)(rbase + j) * N + col] = (_Float16)v;
      }
    }
}

// ---------------- prefix-sum over t (in place), then multiply by C0[t] ----------------
__global__ __launch_bounds__(256) void k_scan(_Float16* __restrict__ V,          // [CH*BB, TWO_N]
                                              const float2* __restrict__ C0c,    // [CH, NN]
                                              float2* __restrict__ ZS, int CH, int first) {
  const int gid = blockIdx.x * 256 + threadIdx.x;  // b*NN + n
  const int n = gid & (NN - 1);
  const int b = gid >> 10;
  float zr, zi;
  if (first) { zr = 0.f; zi = 0.f; }
  else { float2 z = ZS[gid]; zr = z.x; zi = z.y; }
  for (int tt = 0; tt < CH; ++tt) {
    unsigned int* p = ((unsigned int*)(V + (size_t)(tt * BB + b) * TWO_N)) + n;
    union { unsigned int u; _Float16 h2[2]; } cv;
    cv.u = *p;
    zr += (float)cv.h2[0]; zi += (float)cv.h2[1];
    const float2 c = C0c[tt * NN + n];
    cv.h2[0] = (_Float16)(c.x * zr - c.y * zi);
    cv.h2[1] = (_Float16)(c.x * zi + c.y * zr);
    *p = cv.u;
  }
  ZS[gid] = make_float2(zr, zi);
}

// ---------------- reduce over t: s1[b,n'] += sum_t U[t,b,n'] ----------------
__global__ __launch_bounds__(256) void k_reduce(const _Float16* __restrict__ U,  // [CH*BB, TWO_N]
                                                float* __restrict__ s1, int CH, int first) {
  const int gid = blockIdx.x * 256 + threadIdx.x;  // b*TWO_N + n'
  const int np = gid & (TWO_N - 1);
  const int b = gid >> 11;
  float a = first ? 0.f : s1[gid];
  for (int tt = 0; tt < CH; ++tt)
    a += (float)U[(size_t)(tt * BB + b) * TWO_N + np];
  s1[gid] = a;
}

// ---------------- s1c = C1last (*) s1 ----------------
__global__ __launch_bounds__(256) void k_s1c(const float* __restrict__ s1,
                                             const float2* __restrict__ C1last,
                                             float* __restrict__ s1c) {
  const int gid = blockIdx.x * 256 + threadIdx.x;  // b*NN + n
  const int n = gid & (NN - 1);
  const int b = gid >> 10;
  const float sr = s1[b * TWO_N + 2 * n], si = s1[b * TWO_N + 2 * n + 1];
  const float2 c = C1last[n];
  s1c[b * TWO_N + 2 * n]     = c.x * sr - c.y * si;
  s1c[b * TWO_N + 2 * n + 1] = c.x * si + c.y * sr;
}

// ---------------- small naive f32 GEMM ----------------
__global__ __launch_bounds__(256) void k_ngemm(const float* __restrict__ A,
                                               const float* __restrict__ B,
                                               float* __restrict__ C, int M, int N, int K) {
  const int gid = blockIdx.x * 256 + threadIdx.x;
  if (gid >= M * N) return;
  const int col = gid % N;
  const int row = gid / N;
  float a = 0.f;
  for (int k = 0; k < K; ++k) a = fmaf(A[(size_t)row * K + k], B[(size_t)k * N + col], a);
  C[gid] = a;
}

// ---------------- weight packing ----------------
// win (src [DD,NN]) -> BT [TWO_N, TWO_K] f16 (transposed interleaved-complex)
__global__ __launch_bounds__(256) void k_prep_in(const float* __restrict__ r, const float* __restrict__ im,
                                                 _Float16* __restrict__ dst) {
  const int gid = blockIdx.x * 256 + threadIdx.x;  // k*NN + n
  const int n = gid & (NN - 1);
  const int k = gid >> 10;
  const float rv = r[(size_t)k * NN + n], iv = im[(size_t)k * NN + n];
  const size_t base = (size_t)(2 * n) * TWO_K + 2 * k;
  dst[base] = (_Float16)rv;              dst[base + 1] = (_Float16)(-iv);
  dst[base + TWO_K] = (_Float16)iv;      dst[base + TWO_K + 1] = (_Float16)rv;
}
// wout (src [NN,DD]) -> BT [TWO_K, TWO_N] f16
__global__ __launch_bounds__(256) void k_prep_out(const float* __restrict__ r, const float* __restrict__ im,
                                                  _Float16* __restrict__ dst) {
  const int gid = blockIdx.x * 256 + threadIdx.x;  // n*DD + d
  const int d = gid & (DD - 1);
  const int n = gid >> 8;
  const float rv = r[(size_t)n * DD + d], iv = im[(size_t)n * DD + d];
  const size_t base = (size_t)(2 * d) * TWO_N + 2 * n;
  dst[base] = (_Float16)rv;              dst[base + 1] = (_Float16)(-iv);
  dst[base + TWO_N] = (_Float16)iv;      dst[base + TWO_N + 1] = (_Float16)rv;
}
// wout[1] -> standard (non-transposed) f32 [TWO_N, TWO_K]
__global__ __launch_bounds__(256) void k_prep_wout1(const float* __restrict__ r, const float* __restrict__ im,
                                                    float* __restrict__ dst) {
  const int gid = blockIdx.x * 256 + threadIdx.x;  // n*DD + d
  const int d = gid & (DD - 1);
  const int n = gid >> 8;
  const float rv = r[(size_t)n * DD + d], iv = im[(size_t)n * DD + d];
  const size_t b0 = (size_t)(2 * n) * TWO_K + 2 * d;
  dst[b0] = rv;              dst[b0 + 1] = iv;
  dst[b0 + TWO_K] = -iv;     dst[b0 + TWO_K + 1] = rv;
}
// Wfin f32 [TWO_K, 256]: row 2d = outp_r+outp_i ; row 2d+1 = outp_r-outp_i
__global__ __launch_bounds__(256) void k_prep_fin(const float* __restrict__ pr, const float* __restrict__ pi_,
                                                  float* __restrict__ dst) {
  const int gid = blockIdx.x * 256 + threadIdx.x;  // d*256 + s
  const int s = gid & 255;
  const int d = gid >> 8;
  const float a = pr[(size_t)d * 256 + s], b = pi_[(size_t)d * 256 + s];
  dst[(size_t)(2 * d) * 256 + s] = a + b;
  dst[(size_t)(2 * d + 1) * 256 + s] = a - b;
}

extern "C" void kernel_launch(void* const* d_in, const int* in_sizes, int n_in,
                              void* d_out, int out_size, void* d_ws, size_t ws_size,
                              hipStream_t stream) {
  const int* ids      = (const int*)d_in[0];
  const float* emb    = (const float*)d_in[1];
  const float* win_r  = (const float*)d_in[2];
  const float* win_i  = (const float*)d_in[3];
  const float* wout_r = (const float*)d_in[4];
  const float* wout_i = (const float*)d_in[5];
  const float* omega  = (const float*)d_in[6];
  const float* outp_r = (const float*)d_in[7];
  const float* outp_i = (const float*)d_in[8];

  char* ws = (char*)d_ws;
  size_t off = 0;
  auto alloc = [&](size_t bytes) { void* p = ws + off; off += (bytes + 255) & ~(size_t)255; return p; };

  float2* C0     = (float2*)alloc((size_t)S_LEN * NN * 8);
  float2* D0     = (float2*)alloc((size_t)S_LEN * NN * 8);
  float2* D1     = (float2*)alloc((size_t)S_LEN * NN * 8);
  float2* C1last = (float2*)alloc((size_t)NN * 8);
  float2* ZS     = (float2*)alloc((size_t)BB * NN * 8);
  float* hstate  = (float*)alloc((size_t)BB * DD * 2 * 4);
  float* s1      = (float*)alloc((size_t)BB * TWO_N * 4);
  float* s1c     = (float*)alloc((size_t)BB * TWO_N * 4);
  float* xt      = (float*)alloc((size_t)BB * TWO_K * 4);
  _Float16* BTin0  = (_Float16*)alloc((size_t)TWO_N * TWO_K * 2);
  _Float16* BTout0 = (_Float16*)alloc((size_t)TWO_K * TWO_N * 2);
  _Float16* BTin1  = (_Float16*)alloc((size_t)TWO_N * TWO_K * 2);
  float* Wout1f = (float*)alloc((size_t)TWO_N * TWO_K * 4);
  float* Wfin   = (float*)alloc((size_t)TWO_K * 256 * 4);
  const size_t fixed = off;

  int CH = 1024;
  while (CH > 32) {
    size_t need = fixed + (size_t)CH * BB * 2 * (TWO_K + TWO_N + TWO_K) + 3 * 256;
    if (need <= ws_size) break;
    CH >>= 1;
  }
  _Float16* X0 = (_Float16*)alloc((size_t)CH * BB * TWO_K * 2);
  _Float16* VB = (_Float16*)alloc((size_t)CH * BB * TWO_N * 2);
  _Float16* Yc = (_Float16*)alloc((size_t)CH * BB * TWO_K * 2);

  k_rot<<<32, 64, 0, stream>>>(omega, C0, D0, D1, C1last);
  k_prep_in<<<DD * NN / 256, 256, 0, stream>>>(win_r, win_i, BTin0);
  k_prep_in<<<DD * NN / 256, 256, 0, stream>>>(win_r + (size_t)DD * NN, win_i + (size_t)DD * NN, BTin1);
  k_prep_out<<<NN * DD / 256, 256, 0, stream>>>(wout_r, wout_i, BTout0);
  k_prep_wout1<<<NN * DD / 256, 256, 0, stream>>>(wout_r + (size_t)NN * DD, wout_i + (size_t)NN * DD, Wout1f);
  k_prep_fin<<<DD * 256 / 256, 256, 0, stream>>>(outp_r, outp_i, Wfin);

  const int nchunks = S_LEN / CH;
  for (int c = 0; c < nchunks; ++c) {
    const int t0 = c * CH;
    const int M = CH * BB;
    k_h<<<dim3(BB, 4), 64, 0, stream>>>(ids, emb, hstate, X0, t0, CH);
    dim3 g1(TWO_N / 128, M / 128);
    k_gemm<<<g1, 256, 0, stream>>>(X0, BTin0, VB, M, TWO_N, TWO_K, D0 + (size_t)t0 * NN);
    k_scan<<<BB * NN / 256, 256, 0, stream>>>(VB, C0 + (size_t)t0 * NN, ZS, CH, c == 0);
    dim3 g2(TWO_K / 128, M / 128);
    k_gemm<<<g2, 256, 0, stream>>>(VB, BTout0, Yc, M, TWO_K, TWO_N, nullptr);
    k_gemm<<<g1, 256, 0, stream>>>(Yc, BTin1, VB, M, TWO_N, TWO_K, D1 + (size_t)t0 * NN);
    k_reduce<<<BB * TWO_N / 256, 256, 0, stream>>>(VB, s1, CH, c == 0);
  }

  k_s1c<<<BB * NN / 256, 256, 0, stream>>>(s1, C1last, s1c);
  k_ngemm<<<BB * TWO_K / 256, 256, 0, stream>>>(s1c, Wout1f, xt, BB, TWO_K, TWO_N);
  k_ngemm<<<BB * 256 / 256, 256, 0, stream>>>(xt, Wfin, (float*)d_out, BB, 256, TWO_K);
}

// Round 2
// 3008.388 us; speedup vs baseline: 1.2827x; 1.2827x over previous
//
#include <hip/hip_runtime.h>

#define S_LEN 1024
#define BB 128
#define DD 256
#define NN 1024
#define TWO_K 512   // 2*DD
#define TWO_N 2048  // 2*NN

typedef _Float16 half8 __attribute__((ext_vector_type(8)));
typedef float f32x4 __attribute__((ext_vector_type(4)));

__device__ __forceinline__ float wrap2pi(float x) {
  float r = fmodf(x, 6.283185307179586f);
  if (r < 0.f) r += 6.283185307179586f;
  return r;
}
__device__ __forceinline__ int lut_index(float th) {
  float w = wrap2pi(th);
  return ((int)floorf(w * 651.8986469044033f)) & 4095;
}

// ---------------- h recurrence (pointwise over b,d) -> X0 [CH*BB, 2*DD] f16 interleaved ----------------
__global__ __launch_bounds__(64) void k_h(const int* __restrict__ ids,
                                          const float* __restrict__ emb,
                                          float* __restrict__ hstate,
                                          _Float16* __restrict__ X0,
                                          int t0, int CH) {
  __shared__ __align__(16) float2 lut[4096];
  const int tid = threadIdx.x;
  for (int i = tid; i < 4096; i += 64) {
    float ang = 0.0015339807878856412f * (float)i;
    lut[i] = make_float2(sinf(ang), cosf(ang));
  }
  __syncthreads();
  const int b = blockIdx.x;
  const int d = blockIdx.y * 64 + tid;
  float hr, hi;
  if (t0 == 0) { hr = 0.f; hi = 0.f; }
  else { float2 h = ((const float2*)hstate)[b * DD + d]; hr = h.x; hi = h.y; }
  for (int tt = 0; tt < CH; ++tt) {
    const int t = t0 + tt;
    const int id = ids[b * S_LEN + t];
    const float w  = emb[(size_t)id * 512 + d];
    const float bv = emb[(size_t)id * 512 + 256 + d];
    const float wl = 1.f + fabsf(w);
    const float tphi = wrap2pi((float)t * 1.618033988749895f);
    const float thr = hr / wl + bv + tphi;
    const float thi = hi / wl + bv + tphi;
    const float2 a = lut[lut_index(thr)];
    const float2 c = lut[lut_index(thi)];
    hr = a.y * c.y - a.x * c.x;
    hi = a.y * c.x + a.x * c.y;
    union { unsigned int u; _Float16 h2[2]; } pk;
    pk.h2[0] = (_Float16)hr; pk.h2[1] = (_Float16)hi;
    *(((unsigned int*)(X0 + (size_t)(tt * BB + b) * TWO_K)) + d) = pk.u;
  }
  ((float2*)hstate)[b * DD + d] = make_float2(hr, hi);
}

// ---------------- rotation prefix products (f64), per (l,n) ----------------
__global__ __launch_bounds__(64) void k_rot(const float* __restrict__ omega,
                                            float2* __restrict__ C0, float2* __restrict__ D0,
                                            float2* __restrict__ D1, float2* __restrict__ C1last) {
  const int gid = blockIdx.x * 64 + threadIdx.x;  // 0..2047
  if (gid >= 2 * NN) return;
  const int l = gid >> 10, n = gid & (NN - 1);
  const float om = omega[l * NN + n];
  double pr = 1.0, pi = 0.0;
  for (int t = 0; t < S_LEN; ++t) {
    const float th = om + (float)t * 1.618033988749895f;
    const int idx = lut_index(th);
    const float ang = 0.0015339807878856412f * (float)idx;
    const float sn = sinf(ang), cn = cosf(ang);
    const double npr = pr * (double)cn - pi * (double)sn;
    const double npi = pr * (double)sn + pi * (double)cn;
    pr = npr; pi = npi;
    const double m2 = pr * pr + pi * pi;
    const float2 inv = make_float2((float)(pr / m2), (float)(-pi / m2));
    if (l == 0) {
      C0[t * NN + n] = make_float2((float)pr, (float)pi);
      D0[t * NN + n] = inv;
    } else {
      D1[t * NN + n] = inv;
    }
  }
  if (l == 1) C1last[n] = make_float2((float)pr, (float)pi);
}

// ---------------- f16 MFMA GEMM: C = A @ BT^T, optional complex rotation epilogue ----------------
// A [M,K] row-major f16, BT [N,K] row-major f16 (i.e. B transposed), C [M,N] f16.
// rot: nullptr or [M/128, N/2] float2; row-block t = blockIdx.y (BM=128=BB so each tile is one t).
__global__ __launch_bounds__(256, 2) void k_gemm(const _Float16* __restrict__ A,
                                                 const _Float16* __restrict__ BT,
                                                 _Float16* __restrict__ C,
                                                 int M, int N, int K,
                                                 const float2* __restrict__ rot) {
  __shared__ __align__(16) _Float16 As[128 * 64];
  __shared__ __align__(16) _Float16 Bs[128 * 64];
  const int tid = threadIdx.x;
  const int lane = tid & 63;
  const int wave = tid >> 6;
  const int wm = wave >> 1;
  const int wn = wave & 1;
  const int m0 = blockIdx.y * 128;
  const int n0 = blockIdx.x * 128;

  const int srow = lane >> 3;               // row within 8-row chunk
  const int schunk = (lane & 7) ^ srow;     // XOR-swizzled source 16B-chunk

  f32x4 acc[4][4] = {};

  for (int kt = 0; kt < K; kt += 64) {
#pragma unroll
    for (int j = 0; j < 4; ++j) {
      const int c = wave * 4 + j;           // chunk 0..15, covers rows c*8..c*8+7
      const int row = c * 8 + srow;
      const _Float16* srcA = A + (size_t)(m0 + row) * K + kt + schunk * 8;
      __builtin_amdgcn_global_load_lds((const __attribute__((address_space(1))) void*)srcA,
                                       (__attribute__((address_space(3))) void*)(As + c * 512), 16, 0, 0);
      const _Float16* srcB = BT + (size_t)(n0 + row) * K + kt + schunk * 8;
      __builtin_amdgcn_global_load_lds((const __attribute__((address_space(1))) void*)srcB,
                                       (__attribute__((address_space(3))) void*)(Bs + c * 512), 16, 0, 0);
    }
    __syncthreads();
#pragma unroll
    for (int ks = 0; ks < 2; ++ks) {
      half8 af[4], bf[4];
#pragma unroll
      for (int mr = 0; mr < 4; ++mr) {
        const int ar = wm * 64 + mr * 16 + (lane & 15);
        const int p = ((ks * 4) + (lane >> 4)) ^ (ar & 7);
        af[mr] = *(const half8*)(As + ar * 64 + p * 8);
      }
#pragma unroll
      for (int nr = 0; nr < 4; ++nr) {
        const int br = wn * 64 + nr * 16 + (lane & 15);
        const int p = ((ks * 4) + (lane >> 4)) ^ (br & 7);
        bf[nr] = *(const half8*)(Bs + br * 64 + p * 8);
      }
#pragma unroll
      for (int mr = 0; mr < 4; ++mr)
#pragma unroll
        for (int nr = 0; nr < 4; ++nr)
          acc[mr][nr] = __builtin_amdgcn_mfma_f32_16x16x32_f16(af[mr], bf[nr], acc[mr][nr], 0, 0, 0);
    }
    __syncthreads();
  }

  const int halfN = N >> 1;
  const int t = blockIdx.y;
#pragma unroll
  for (int mr = 0; mr < 4; ++mr)
#pragma unroll
    for (int nr = 0; nr < 4; ++nr) {
      const int col = n0 + wn * 64 + nr * 16 + (lane & 15);
      const int rbase = m0 + wm * 64 + mr * 16 + ((lane >> 4) << 2);
      float2 dr = make_float2(1.f, 0.f);
      if (rot) dr = rot[(size_t)t * halfN + (col >> 1)];
#pragma unroll
      for (int j = 0; j < 4; ++j) {
        float v = acc[mr][nr][j];
        if (rot) {
          const float pv = __shfl_xor(v, 1);
          v = (lane & 1) ? (dr.x * v + dr.y * pv) : (dr.x * v - dr.y * pv);
        }
        C[(size_t)(rbase + j) * N + col] = (_Float16)v;
      }
    }
}

// ---------------- prefix-sum over t (in place), then multiply by C0[t] ----------------
__global__ __launch_bounds__(256) void k_scan(_Float16* __restrict__ V,          // [CH*BB, TWO_N]
                                              const float2* __restrict__ C0c,    // [CH, NN]
                                              float2* __restrict__ ZS, int CH, int first) {
  const int gid = blockIdx.x * 256 + threadIdx.x;  // b*NN + n
  const int n = gid & (NN - 1);
  const int b = gid >> 10;
  float zr, zi;
  if (first) { zr = 0.f; zi = 0.f; }
  else { float2 z = ZS[gid]; zr = z.x; zi = z.y; }
  for (int tt = 0; tt < CH; ++tt) {
    unsigned int* p = ((unsigned int*)(V + (size_t)(tt * BB + b) * TWO_N)) + n;
    union { unsigned int u; _Float16 h2[2]; } cv;
    cv.u = *p;
    zr += (float)cv.h2[0]; zi += (float)cv.h2[1];
    const float2 c = C0c[tt * NN + n];
    cv.h2[0] = (_Float16)(c.x * zr - c.y * zi);
    cv.h2[1] = (_Float16)(c.x * zi + c.y * zr);
    *p = cv.u;
  }
  ZS[gid] = make_float2(zr, zi);
}

// ---------------- reduce over t: s1[b,n'] += sum_t U[t,b,n'] ----------------
__global__ __launch_bounds__(256) void k_reduce(const _Float16* __restrict__ U,  // [CH*BB, TWO_N]
                                                float* __restrict__ s1, int CH, int first) {
  const int gid = blockIdx.x * 256 + threadIdx.x;  // b*TWO_N + n'
  const int np = gid & (TWO_N - 1);
  const int b = gid >> 11;
  float a = first ? 0.f : s1[gid];
  for (int tt = 0; tt < CH; ++tt)
    a += (float)U[(size_t)(tt * BB + b) * TWO_N + np];
  s1[gid] = a;
}

// ---------------- s1c = C1last (*) s1 ----------------
__global__ __launch_bounds__(256) void k_s1c(const float* __restrict__ s1,
                                             const float2* __restrict__ C1last,
                                             float* __restrict__ s1c) {
  const int gid = blockIdx.x * 256 + threadIdx.x;  // b*NN + n
  const int n = gid & (NN - 1);
  const int b = gid >> 10;
  const float sr = s1[b * TWO_N + 2 * n], si = s1[b * TWO_N + 2 * n + 1];
  const float2 c = C1last[n];
  s1c[b * TWO_N + 2 * n]     = c.x * sr - c.y * si;
  s1c[b * TWO_N + 2 * n + 1] = c.x * si + c.y * sr;
}

// ---------------- tail GEMM: one wave per output, A [M,K] f32, BT [N,K] f32 ----------------
__global__ __launch_bounds__(256) void k_tail(const float* __restrict__ A,
                                              const float* __restrict__ BT,
                                              float* __restrict__ C, int M, int N, int K) {
  const int wave = threadIdx.x >> 6;
  const int lane = threadIdx.x & 63;
  const int o = blockIdx.x * 4 + wave;     // output index
  if (o >= M * N) return;
  const int row = o / N;
  const int col = o - row * N;
  const float4* __restrict__ a4 = (const float4*)(A + (size_t)row * K);
  const float4* __restrict__ b4 = (const float4*)(BT + (size_t)col * K);
  float acc = 0.f;
  const int nit = K >> 8;                  // K / (64 lanes * 4)
  for (int it = 0; it < nit; ++it) {
    const float4 av = a4[it * 64 + lane];
    const float4 bv = b4[it * 64 + lane];
    acc = fmaf(av.x, bv.x, acc);
    acc = fmaf(av.y, bv.y, acc);
    acc = fmaf(av.z, bv.z, acc);
    acc = fmaf(av.w, bv.w, acc);
  }
#pragma unroll
  for (int s = 32; s >= 1; s >>= 1) acc += __shfl_xor(acc, s);
  if (lane == 0) C[o] = acc;
}

// ---------------- weight packing ----------------
// win (src [DD,NN]) -> BT [TWO_N, TWO_K] f16 (transposed interleaved-complex)
__global__ __launch_bounds__(256) void k_prep_in(const float* __restrict__ r, const float* __restrict__ im,
                                                 _Float16* __restrict__ dst) {
  const int gid = blockIdx.x * 256 + threadIdx.x;  // k*NN + n
  const int n = gid & (NN - 1);
  const int k = gid >> 10;
  const float rv = r[(size_t)k * NN + n], iv = im[(size_t)k * NN + n];
  const size_t base = (size_t)(2 * n) * TWO_K + 2 * k;
  dst[base] = (_Float16)rv;              dst[base + 1] = (_Float16)(-iv);
  dst[base + TWO_K] = (_Float16)iv;      dst[base + TWO_K + 1] = (_Float16)rv;
}
// wout (src [NN,DD]) -> BT [TWO_K, TWO_N] f16
__global__ __launch_bounds__(256) void k_prep_out(const float* __restrict__ r, const float* __restrict__ im,
                                                  _Float16* __restrict__ dst) {
  const int gid = blockIdx.x * 256 + threadIdx.x;  // n*DD + d
  const int d = gid & (DD - 1);
  const int n = gid >> 8;
  const float rv = r[(size_t)n * DD + d], iv = im[(size_t)n * DD + d];
  const size_t base = (size_t)(2 * d) * TWO_N + 2 * n;
  dst[base] = (_Float16)rv;              dst[base + 1] = (_Float16)(-iv);
  dst[base + TWO_N] = (_Float16)iv;      dst[base + TWO_N + 1] = (_Float16)rv;
}
// wout[1] (src [NN,DD]) -> transposed f32 [TWO_K, TWO_N]: WT[j,i] = Wout1[i,j]
__global__ __launch_bounds__(256) void k_prep_wout1T(const float* __restrict__ r, const float* __restrict__ im,
                                                     float* __restrict__ dstT) {
  const int gid = blockIdx.x * 256 + threadIdx.x;  // d*NN + n
  const int n = gid & (NN - 1);
  const int d = gid >> 10;
  const float rv = r[(size_t)n * DD + d], iv = im[(size_t)n * DD + d];
  const size_t b0 = (size_t)(2 * d) * TWO_N + 2 * n;
  const size_t b1 = (size_t)(2 * d + 1) * TWO_N + 2 * n;
  dstT[b0] = rv;     dstT[b0 + 1] = -iv;
  dstT[b1] = iv;     dstT[b1 + 1] = rv;
}
// Wfin transposed f32 [256, TWO_K]: WfinT[s, 2d] = pr+pi ; WfinT[s, 2d+1] = pr-pi
__global__ __launch_bounds__(256) void k_prep_finT(const float* __restrict__ pr, const float* __restrict__ pi_,
                                                   float* __restrict__ dstT) {
  const int gid = blockIdx.x * 256 + threadIdx.x;  // s*DD + d
  const int d = gid & (DD - 1);
  const int s = gid >> 8;
  const float a = pr[(size_t)d * 256 + s], b = pi_[(size_t)d * 256 + s];
  dstT[(size_t)s * TWO_K + 2 * d] = a + b;
  dstT[(size_t)s * TWO_K + 2 * d + 1] = a - b;
}

extern "C" void kernel_launch(void* const* d_in, const int* in_sizes, int n_in,
                              void* d_out, int out_size, void* d_ws, size_t ws_size,
                              hipStream_t stream) {
  const int* ids      = (const int*)d_in[0];
  const float* emb    = (const float*)d_in[1];
  const float* win_r  = (const float*)d_in[2];
  const float* win_i  = (const float*)d_in[3];
  const float* wout_r = (const float*)d_in[4];
  const float* wout_i = (const float*)d_in[5];
  const float* omega  = (const float*)d_in[6];
  const float* outp_r = (const float*)d_in[7];
  const float* outp_i = (const float*)d_in[8];

  char* ws = (char*)d_ws;
  size_t off = 0;
  auto alloc = [&](size_t bytes) { void* p = ws + off; off += (bytes + 255) & ~(size_t)255; return p; };

  float2* C0     = (float2*)alloc((size_t)S_LEN * NN * 8);
  float2* D0     = (float2*)alloc((size_t)S_LEN * NN * 8);
  float2* D1     = (float2*)alloc((size_t)S_LEN * NN * 8);
  float2* C1last = (float2*)alloc((size_t)NN * 8);
  float2* ZS     = (float2*)alloc((size_t)BB * NN * 8);
  float* hstate  = (float*)alloc((size_t)BB * DD * 2 * 4);
  float* s1      = (float*)alloc((size_t)BB * TWO_N * 4);
  float* s1c     = (float*)alloc((size_t)BB * TWO_N * 4);
  float* xt      = (float*)alloc((size_t)BB * TWO_K * 4);
  _Float16* BTin0  = (_Float16*)alloc((size_t)TWO_N * TWO_K * 2);
  _Float16* BTout0 = (_Float16*)alloc((size_t)TWO_K * TWO_N * 2);
  _Float16* BTin1  = (_Float16*)alloc((size_t)TWO_N * TWO_K * 2);
  float* Wout1T = (float*)alloc((size_t)TWO_K * TWO_N * 4);
  float* WfinT  = (float*)alloc((size_t)256 * TWO_K * 4);
  const size_t fixed = off;

  int CH = 1024;
  while (CH > 32) {
    size_t need = fixed + (size_t)CH * BB * 2 * (TWO_K + TWO_N + TWO_K) + 3 * 256;
    if (need <= ws_size) break;
    CH >>= 1;
  }
  _Float16* X0 = (_Float16*)alloc((size_t)CH * BB * TWO_K * 2);
  _Float16* VB = (_Float16*)alloc((size_t)CH * BB * TWO_N * 2);
  _Float16* Yc = (_Float16*)alloc((size_t)CH * BB * TWO_K * 2);

  k_rot<<<32, 64, 0, stream>>>(omega, C0, D0, D1, C1last);
  k_prep_in<<<DD * NN / 256, 256, 0, stream>>>(win_r, win_i, BTin0);
  k_prep_in<<<DD * NN / 256, 256, 0, stream>>>(win_r + (size_t)DD * NN, win_i + (size_t)DD * NN, BTin1);
  k_prep_out<<<NN * DD / 256, 256, 0, stream>>>(wout_r, wout_i, BTout0);
  k_prep_wout1T<<<NN * DD / 256, 256, 0, stream>>>(wout_r + (size_t)NN * DD, wout_i + (size_t)NN * DD, Wout1T);
  k_prep_finT<<<DD * 256 / 256, 256, 0, stream>>>(outp_r, outp_i, WfinT);

  const int nchunks = S_LEN / CH;
  for (int c = 0; c < nchunks; ++c) {
    const int t0 = c * CH;
    const int M = CH * BB;
    k_h<<<dim3(BB, 4), 64, 0, stream>>>(ids, emb, hstate, X0, t0, CH);
    dim3 g1(TWO_N / 128, M / 128);
    k_gemm<<<g1, 256, 0, stream>>>(X0, BTin0, VB, M, TWO_N, TWO_K, D0 + (size_t)t0 * NN);
    k_scan<<<BB * NN / 256, 256, 0, stream>>>(VB, C0 + (size_t)t0 * NN, ZS, CH, c == 0);
    dim3 g2(TWO_K / 128, M / 128);
    k_gemm<<<g2, 256, 0, stream>>>(VB, BTout0, Yc, M, TWO_K, TWO_N, nullptr);
    k_gemm<<<g1, 256, 0, stream>>>(Yc, BTin1, VB, M, TWO_N, TWO_K, D1 + (size_t)t0 * NN);
    k_reduce<<<BB * TWO_N / 256, 256, 0, stream>>>(VB, s1, CH, c == 0);
  }

  k_s1c<<<BB * NN / 256, 256, 0, stream>>>(s1, C1last, s1c);
  // xt[128, 512] = s1c[128, 2048] @ Wout1 (via Wout1T [512, 2048])
  k_tail<<<BB * TWO_K / 4, 256, 0, stream>>>(s1c, Wout1T, xt, BB, TWO_K, TWO_N);
  // out[128, 256] = xt[128, 512] @ Wfin (via WfinT [256, 512])
  k_tail<<<BB * 256 / 4, 256, 0, stream>>>(xt, WfinT, (float*)d_out, BB, 256, TWO_K);
}

// Round 3
// 2903.855 us; speedup vs baseline: 1.3289x; 1.0360x over previous
//
#include <hip/hip_runtime.h>

#define S_LEN 1024
#define BB 128
#define DD 256
#define NN 1024
#define TWO_K 512   // 2*DD
#define TWO_N 2048  // 2*NN

typedef _Float16 half8 __attribute__((ext_vector_type(8)));
typedef float f32x4 __attribute__((ext_vector_type(4)));
typedef float f32x8 __attribute__((ext_vector_type(8)));

__device__ __forceinline__ float wrap2pi(float x) {
  float r = fmodf(x, 6.283185307179586f);
  if (r < 0.f) r += 6.283185307179586f;
  return r;
}
__device__ __forceinline__ int lut_index(float th) {
  float w = wrap2pi(th);
  return ((int)floorf(w * 651.8986469044033f)) & 4095;
}

// ---------------- h recurrence (pointwise over b,d) -> X0 [CH*BB, 2*DD] f16 interleaved ----------------
__global__ __launch_bounds__(64) void k_h(const int* __restrict__ ids,
                                          const float* __restrict__ emb,
                                          float* __restrict__ hstate,
                                          _Float16* __restrict__ X0,
                                          int t0, int CH) {
  __shared__ __align__(16) float2 lut[4096];
  const int tid = threadIdx.x;
  for (int i = tid; i < 4096; i += 64) {
    float ang = 0.0015339807878856412f * (float)i;
    lut[i] = make_float2(sinf(ang), cosf(ang));
  }
  __syncthreads();
  const int b = blockIdx.x;
  const int d = blockIdx.y * 64 + tid;
  float hr, hi;
  if (t0 == 0) { hr = 0.f; hi = 0.f; }
  else { float2 h = ((const float2*)hstate)[b * DD + d]; hr = h.x; hi = h.y; }
  for (int tt = 0; tt < CH; ++tt) {
    const int t = t0 + tt;
    const int id = ids[b * S_LEN + t];
    const float w  = emb[(size_t)id * 512 + d];
    const float bv = emb[(size_t)id * 512 + 256 + d];
    const float wl = 1.f + fabsf(w);
    const float tphi = wrap2pi((float)t * 1.618033988749895f);
    const float thr = hr / wl + bv + tphi;
    const float thi = hi / wl + bv + tphi;
    const float2 a = lut[lut_index(thr)];
    const float2 c = lut[lut_index(thi)];
    hr = a.y * c.y - a.x * c.x;
    hi = a.y * c.x + a.x * c.y;
    union { unsigned int u; _Float16 h2[2]; } pk;
    pk.h2[0] = (_Float16)hr; pk.h2[1] = (_Float16)hi;
    *(((unsigned int*)(X0 + (size_t)(tt * BB + b) * TWO_K)) + d) = pk.u;
  }
  ((float2*)hstate)[b * DD + d] = make_float2(hr, hi);
}

// ---------------- rotation prefix via integer angle prefix-sum + LDS LUT ----------------
// C[t] = rot by (2*pi/4096)*S_t, S_t = prefix sum of LUT indices; D[t] = conj(C[t]).
__global__ __launch_bounds__(256) void k_rot(const float* __restrict__ omega,
                                             float2* __restrict__ C0, float2* __restrict__ D0,
                                             float2* __restrict__ D1, float2* __restrict__ C1last) {
  __shared__ __align__(16) float2 lut[4096];  // (sin, cos)
  for (int i = threadIdx.x; i < 4096; i += 256) {
    float ang = 0.0015339807878856412f * (float)i;
    lut[i] = make_float2(sinf(ang), cosf(ang));
  }
  __syncthreads();
  const int gid = blockIdx.x * 256 + threadIdx.x;  // 0..2047
  const int l = gid >> 10, n = gid & (NN - 1);
  const float om = omega[l * NN + n];
  int acc = 0;
  float lc = 1.f, ls = 0.f;
  for (int t = 0; t < S_LEN; ++t) {
    acc += lut_index(om + (float)t * 1.618033988749895f);
    const float2 cs = lut[acc & 4095];
    lc = cs.y; ls = cs.x;
    if (l == 0) {
      C0[t * NN + n] = make_float2(lc, ls);
      D0[t * NN + n] = make_float2(lc, -ls);
    } else {
      D1[t * NN + n] = make_float2(lc, -ls);
    }
  }
  if (l == 1) C1last[n] = make_float2(lc, ls);
}

// ---------------- f16 MFMA GEMM: C = A @ BT^T, optional complex rotation epilogue ----------------
// A [M,K] row-major f16, BT [N,K] row-major f16 (i.e. B transposed), C [M,N] f16.
// rot: nullptr or [M/128, N/2] float2; row-block t = blockIdx.y (BM=128=BB so each tile is one t).
__global__ __launch_bounds__(256, 2) void k_gemm(const _Float16* __restrict__ A,
                                                 const _Float16* __restrict__ BT,
                                                 _Float16* __restrict__ C,
                                                 int M, int N, int K,
                                                 const float2* __restrict__ rot) {
  __shared__ __align__(16) _Float16 As[128 * 64];
  __shared__ __align__(16) _Float16 Bs[128 * 64];
  const int tid = threadIdx.x;
  const int lane = tid & 63;
  const int wave = tid >> 6;
  const int wm = wave >> 1;
  const int wn = wave & 1;
  const int m0 = blockIdx.y * 128;
  const int n0 = blockIdx.x * 128;

  const int srow = lane >> 3;               // row within 8-row chunk
  const int schunk = (lane & 7) ^ srow;     // XOR-swizzled source 16B-chunk

  f32x4 acc[4][4] = {};

  for (int kt = 0; kt < K; kt += 64) {
#pragma unroll
    for (int j = 0; j < 4; ++j) {
      const int c = wave * 4 + j;           // chunk 0..15, covers rows c*8..c*8+7
      const int row = c * 8 + srow;
      const _Float16* srcA = A + (size_t)(m0 + row) * K + kt + schunk * 8;
      __builtin_amdgcn_global_load_lds((const __attribute__((address_space(1))) void*)srcA,
                                       (__attribute__((address_space(3))) void*)(As + c * 512), 16, 0, 0);
      const _Float16* srcB = BT + (size_t)(n0 + row) * K + kt + schunk * 8;
      __builtin_amdgcn_global_load_lds((const __attribute__((address_space(1))) void*)srcB,
                                       (__attribute__((address_space(3))) void*)(Bs + c * 512), 16, 0, 0);
    }
    __syncthreads();
#pragma unroll
    for (int ks = 0; ks < 2; ++ks) {
      half8 af[4], bf[4];
#pragma unroll
      for (int mr = 0; mr < 4; ++mr) {
        const int ar = wm * 64 + mr * 16 + (lane & 15);
        const int p = ((ks * 4) + (lane >> 4)) ^ (ar & 7);
        af[mr] = *(const half8*)(As + ar * 64 + p * 8);
      }
#pragma unroll
      for (int nr = 0; nr < 4; ++nr) {
        const int br = wn * 64 + nr * 16 + (lane & 15);
        const int p = ((ks * 4) + (lane >> 4)) ^ (br & 7);
        bf[nr] = *(const half8*)(Bs + br * 64 + p * 8);
      }
#pragma unroll
      for (int mr = 0; mr < 4; ++mr)
#pragma unroll
        for (int nr = 0; nr < 4; ++nr)
          acc[mr][nr] = __builtin_amdgcn_mfma_f32_16x16x32_f16(af[mr], bf[nr], acc[mr][nr], 0, 0, 0);
    }
    __syncthreads();
  }

  const int halfN = N >> 1;
  const int t = blockIdx.y;
#pragma unroll
  for (int mr = 0; mr < 4; ++mr)
#pragma unroll
    for (int nr = 0; nr < 4; ++nr) {
      const int col = n0 + wn * 64 + nr * 16 + (lane & 15);
      const int rbase = m0 + wm * 64 + mr * 16 + ((lane >> 4) << 2);
      float2 dr = make_float2(1.f, 0.f);
      if (rot) dr = rot[(size_t)t * halfN + (col >> 1)];
#pragma unroll
      for (int j = 0; j < 4; ++j) {
        float v = acc[mr][nr][j];
        if (rot) {
          const float pv = __shfl_xor(v, 1);
          v = (lane & 1) ? (dr.x * v + dr.y * pv) : (dr.x * v - dr.y * pv);
        }
        C[(size_t)(rbase + j) * N + col] = (_Float16)v;
      }
    }
}

// ---------------- prefix-sum over t (in place), then multiply by C0[t]; 2 complex/thread ----------------
__global__ __launch_bounds__(256) void k_scan(_Float16* __restrict__ V,          // [CH*BB, TWO_N]
                                              const float2* __restrict__ C0c,    // [CH, NN]
                                              float2* __restrict__ ZS, int CH, int first) {
  const int gid = blockIdx.x * 256 + threadIdx.x;  // b*(NN/2) + npair
  const int npair = gid & (NN / 2 - 1);
  const int b = gid >> 9;
  const int n = npair * 2;
  float zr0, zi0, zr1, zi1;
  if (first) { zr0 = zi0 = zr1 = zi1 = 0.f; }
  else {
    float4 z = *(const float4*)(ZS + (size_t)b * NN + n);
    zr0 = z.x; zi0 = z.y; zr1 = z.z; zi1 = z.w;
  }
  for (int tt = 0; tt < CH; ++tt) {
    uint2* p = (uint2*)(((unsigned int*)(V + (size_t)(tt * BB + b) * TWO_N)) + n);
    uint2 cv = *p;
    union { unsigned int u; _Float16 h2[2]; } a, c;
    a.u = cv.x; c.u = cv.y;
    zr0 += (float)a.h2[0]; zi0 += (float)a.h2[1];
    zr1 += (float)c.h2[0]; zi1 += (float)c.h2[1];
    const float4 cc = *(const float4*)(C0c + (size_t)tt * NN + n);
    a.h2[0] = (_Float16)(cc.x * zr0 - cc.y * zi0);
    a.h2[1] = (_Float16)(cc.x * zi0 + cc.y * zr0);
    c.h2[0] = (_Float16)(cc.z * zr1 - cc.w * zi1);
    c.h2[1] = (_Float16)(cc.z * zi1 + cc.w * zr1);
    *p = make_uint2(a.u, c.u);
  }
  *(float4*)(ZS + (size_t)b * NN + n) = make_float4(zr0, zi0, zr1, zi1);
}

// ---------------- reduce over t: s1[b, n'8] += sum_t U[t,b,n'8], half8 vectorized ----------------
__global__ __launch_bounds__(256) void k_reduce(const _Float16* __restrict__ U,  // [CH*BB, TWO_N]
                                                float* __restrict__ s1, int CH, int first) {
  const int gid = blockIdx.x * 256 + threadIdx.x;  // b*(TWO_N/8) + g
  const int g = gid & (TWO_N / 8 - 1);
  const int b = gid >> 8;
  const int np = g * 8;
  f32x8 acc;
  if (first) {
#pragma unroll
    for (int j = 0; j < 8; ++j) acc[j] = 0.f;
  } else {
    acc = *(const f32x8*)(s1 + (size_t)b * TWO_N + np);
  }
  for (int tt = 0; tt < CH; ++tt) {
    const half8 v = *(const half8*)(U + (size_t)(tt * BB + b) * TWO_N + np);
#pragma unroll
    for (int j = 0; j < 8; ++j) acc[j] += (float)v[j];
  }
  *(f32x8*)(s1 + (size_t)b * TWO_N + np) = acc;
}

// ---------------- s1c = C1last (*) s1 ----------------
__global__ __launch_bounds__(256) void k_s1c(const float* __restrict__ s1,
                                             const float2* __restrict__ C1last,
                                             float* __restrict__ s1c) {
  const int gid = blockIdx.x * 256 + threadIdx.x;  // b*NN + n
  const int n = gid & (NN - 1);
  const int b = gid >> 10;
  const float sr = s1[b * TWO_N + 2 * n], si = s1[b * TWO_N + 2 * n + 1];
  const float2 c = C1last[n];
  s1c[b * TWO_N + 2 * n]     = c.x * sr - c.y * si;
  s1c[b * TWO_N + 2 * n + 1] = c.x * si + c.y * sr;
}

// ---------------- tail GEMM: one wave per output, A [M,K] f32, BT [N,K] f32 ----------------
__global__ __launch_bounds__(256) void k_tail(const float* __restrict__ A,
                                              const float* __restrict__ BT,
                                              float* __restrict__ C, int M, int N, int K) {
  const int wave = threadIdx.x >> 6;
  const int lane = threadIdx.x & 63;
  const int o = blockIdx.x * 4 + wave;     // output index
  if (o >= M * N) return;
  const int row = o / N;
  const int col = o - row * N;
  const float4* __restrict__ a4 = (const float4*)(A + (size_t)row * K);
  const float4* __restrict__ b4 = (const float4*)(BT + (size_t)col * K);
  float acc = 0.f;
  const int nit = K >> 8;                  // K / (64 lanes * 4)
  for (int it = 0; it < nit; ++it) {
    const float4 av = a4[it * 64 + lane];
    const float4 bv = b4[it * 64 + lane];
    acc = fmaf(av.x, bv.x, acc);
    acc = fmaf(av.y, bv.y, acc);
    acc = fmaf(av.z, bv.z, acc);
    acc = fmaf(av.w, bv.w, acc);
  }
#pragma unroll
  for (int s = 32; s >= 1; s >>= 1) acc += __shfl_xor(acc, s);
  if (lane == 0) C[o] = acc;
}

// ---------------- weight packing ----------------
// win (src [DD,NN]) -> BT [TWO_N, TWO_K] f16 (transposed interleaved-complex)
__global__ __launch_bounds__(256) void k_prep_in(const float* __restrict__ r, const float* __restrict__ im,
                                                 _Float16* __restrict__ dst) {
  const int gid = blockIdx.x * 256 + threadIdx.x;  // k*NN + n
  const int n = gid & (NN - 1);
  const int k = gid >> 10;
  const float rv = r[(size_t)k * NN + n], iv = im[(size_t)k * NN + n];
  const size_t base = (size_t)(2 * n) * TWO_K + 2 * k;
  dst[base] = (_Float16)rv;              dst[base + 1] = (_Float16)(-iv);
  dst[base + TWO_K] = (_Float16)iv;      dst[base + TWO_K + 1] = (_Float16)rv;
}
// wout (src [NN,DD]) -> BT [TWO_K, TWO_N] f16
__global__ __launch_bounds__(256) void k_prep_out(const float* __restrict__ r, const float* __restrict__ im,
                                                  _Float16* __restrict__ dst) {
  const int gid = blockIdx.x * 256 + threadIdx.x;  // n*DD + d
  const int d = gid & (DD - 1);
  const int n = gid >> 8;
  const float rv = r[(size_t)n * DD + d], iv = im[(size_t)n * DD + d];
  const size_t base = (size_t)(2 * d) * TWO_N + 2 * n;
  dst[base] = (_Float16)rv;              dst[base + 1] = (_Float16)(-iv);
  dst[base + TWO_N] = (_Float16)iv;      dst[base + TWO_N + 1] = (_Float16)rv;
}
// wout[1] (src [NN,DD]) -> transposed f32 [TWO_K, TWO_N]: WT[j,i] = Wout1[i,j]
__global__ __launch_bounds__(256) void k_prep_wout1T(const float* __restrict__ r, const float* __restrict__ im,
                                                     float* __restrict__ dstT) {
  const int gid = blockIdx.x * 256 + threadIdx.x;  // d*NN + n
  const int n = gid & (NN - 1);
  const int d = gid >> 10;
  const float rv = r[(size_t)n * DD + d], iv = im[(size_t)n * DD + d];
  const size_t b0 = (size_t)(2 * d) * TWO_N + 2 * n;
  const size_t b1 = (size_t)(2 * d + 1) * TWO_N + 2 * n;
  dstT[b0] = rv;     dstT[b0 + 1] = -iv;
  dstT[b1] = iv;     dstT[b1 + 1] = rv;
}
// Wfin transposed f32 [256, TWO_K]: WfinT[s, 2d] = pr+pi ; WfinT[s, 2d+1] = pr-pi
__global__ __launch_bounds__(256) void k_prep_finT(const float* __restrict__ pr, const float* __restrict__ pi_,
                                                   float* __restrict__ dstT) {
  const int gid = blockIdx.x * 256 + threadIdx.x;  // s*DD + d
  const int d = gid & (DD - 1);
  const int s = gid >> 8;
  const float a = pr[(size_t)d * 256 + s], b = pi_[(size_t)d * 256 + s];
  dstT[(size_t)s * TWO_K + 2 * d] = a + b;
  dstT[(size_t)s * TWO_K + 2 * d + 1] = a - b;
}

extern "C" void kernel_launch(void* const* d_in, const int* in_sizes, int n_in,
                              void* d_out, int out_size, void* d_ws, size_t ws_size,
                              hipStream_t stream) {
  const int* ids      = (const int*)d_in[0];
  const float* emb    = (const float*)d_in[1];
  const float* win_r  = (const float*)d_in[2];
  const float* win_i  = (const float*)d_in[3];
  const float* wout_r = (const float*)d_in[4];
  const float* wout_i = (const float*)d_in[5];
  const float* omega  = (const float*)d_in[6];
  const float* outp_r = (const float*)d_in[7];
  const float* outp_i = (const float*)d_in[8];

  char* ws = (char*)d_ws;
  size_t off = 0;
  auto alloc = [&](size_t bytes) { void* p = ws + off; off += (bytes + 255) & ~(size_t)255; return p; };

  float2* C0     = (float2*)alloc((size_t)S_LEN * NN * 8);
  float2* D0     = (float2*)alloc((size_t)S_LEN * NN * 8);
  float2* D1     = (float2*)alloc((size_t)S_LEN * NN * 8);
  float2* C1last = (float2*)alloc((size_t)NN * 8);
  float2* ZS     = (float2*)alloc((size_t)BB * NN * 8);
  float* hstate  = (float*)alloc((size_t)BB * DD * 2 * 4);
  float* s1      = (float*)alloc((size_t)BB * TWO_N * 4);
  float* s1c     = (float*)alloc((size_t)BB * TWO_N * 4);
  float* xt      = (float*)alloc((size_t)BB * TWO_K * 4);
  _Float16* BTin0  = (_Float16*)alloc((size_t)TWO_N * TWO_K * 2);
  _Float16* BTout0 = (_Float16*)alloc((size_t)TWO_K * TWO_N * 2);
  _Float16* BTin1  = (_Float16*)alloc((size_t)TWO_N * TWO_K * 2);
  float* Wout1T = (float*)alloc((size_t)TWO_K * TWO_N * 4);
  float* WfinT  = (float*)alloc((size_t)256 * TWO_K * 4);
  const size_t fixed = off;

  int CH = 1024;
  while (CH > 32) {
    size_t need = fixed + (size_t)CH * BB * 2 * (TWO_K + TWO_N + TWO_K) + 3 * 256;
    if (need <= ws_size) break;
    CH >>= 1;
  }
  _Float16* X0 = (_Float16*)alloc((size_t)CH * BB * TWO_K * 2);
  _Float16* VB = (_Float16*)alloc((size_t)CH * BB * TWO_N * 2);
  _Float16* Yc = (_Float16*)alloc((size_t)CH * BB * TWO_K * 2);

  k_rot<<<8, 256, 0, stream>>>(omega, C0, D0, D1, C1last);
  k_prep_in<<<DD * NN / 256, 256, 0, stream>>>(win_r, win_i, BTin0);
  k_prep_in<<<DD * NN / 256, 256, 0, stream>>>(win_r + (size_t)DD * NN, win_i + (size_t)DD * NN, BTin1);
  k_prep_out<<<NN * DD / 256, 256, 0, stream>>>(wout_r, wout_i, BTout0);
  k_prep_wout1T<<<NN * DD / 256, 256, 0, stream>>>(wout_r + (size_t)NN * DD, wout_i + (size_t)NN * DD, Wout1T);
  k_prep_finT<<<DD * 256 / 256, 256, 0, stream>>>(outp_r, outp_i, WfinT);

  const int nchunks = S_LEN / CH;
  for (int c = 0; c < nchunks; ++c) {
    const int t0 = c * CH;
    const int M = CH * BB;
    k_h<<<dim3(BB, 4), 64, 0, stream>>>(ids, emb, hstate, X0, t0, CH);
    dim3 g1(TWO_N / 128, M / 128);
    k_gemm<<<g1, 256, 0, stream>>>(X0, BTin0, VB, M, TWO_N, TWO_K, D0 + (size_t)t0 * NN);
    k_scan<<<BB * (NN / 2) / 256, 256, 0, stream>>>(VB, C0 + (size_t)t0 * NN, ZS, CH, c == 0);
    dim3 g2(TWO_K / 128, M / 128);
    k_gemm<<<g2, 256, 0, stream>>>(VB, BTout0, Yc, M, TWO_K, TWO_N, nullptr);
    k_gemm<<<g1, 256, 0, stream>>>(Yc, BTin1, VB, M, TWO_N, TWO_K, D1 + (size_t)t0 * NN);
    k_reduce<<<BB * (TWO_N / 8) / 256, 256, 0, stream>>>(VB, s1, CH, c == 0);
  }

  k_s1c<<<BB * NN / 256, 256, 0, stream>>>(s1, C1last, s1c);
  // xt[128, 512] = s1c[128, 2048] @ Wout1 (via Wout1T [512, 2048])
  k_tail<<<BB * TWO_K / 4, 256, 0, stream>>>(s1c, Wout1T, xt, BB, TWO_K, TWO_N);
  // out[128, 256] = xt[128, 512] @ Wfin (via WfinT [256, 512])
  k_tail<<<BB * 256 / 4, 256, 0, stream>>>(xt, WfinT, (float*)d_out, BB, 256, TWO_K);
}

// Round 4
// 2753.336 us; speedup vs baseline: 1.4015x; 1.0547x over previous
//
#include <hip/hip_runtime.h>

#define S_LEN 1024
#define BB 128
#define DD 256
#define NN 1024
#define TWO_K 512   // 2*DD
#define TWO_N 2048  // 2*NN

typedef _Float16 half8 __attribute__((ext_vector_type(8)));
typedef float f32x4 __attribute__((ext_vector_type(4)));
typedef float f32x8 __attribute__((ext_vector_type(8)));

__device__ __forceinline__ float wrap2pi(float x) {
  float r = fmodf(x, 6.283185307179586f);
  if (r < 0.f) r += 6.283185307179586f;
  return r;
}
__device__ __forceinline__ int lut_index(float th) {
  float w = wrap2pi(th);
  return ((int)floorf(w * 651.8986469044033f)) & 4095;
}

// ---------------- h recurrence (pointwise over b,d) -> X0 [CH*BB, 2*DD] f16 interleaved ----------------
__global__ __launch_bounds__(64) void k_h(const int* __restrict__ ids,
                                          const float* __restrict__ emb,
                                          float* __restrict__ hstate,
                                          _Float16* __restrict__ X0,
                                          int t0, int CH) {
  __shared__ __align__(16) float2 lut[4096];
  const int tid = threadIdx.x;
  for (int i = tid; i < 4096; i += 64) {
    float ang = 0.0015339807878856412f * (float)i;
    lut[i] = make_float2(sinf(ang), cosf(ang));
  }
  __syncthreads();
  const int b = blockIdx.x;
  const int d = blockIdx.y * 64 + tid;
  float hr, hi;
  if (t0 == 0) { hr = 0.f; hi = 0.f; }
  else { float2 h = ((const float2*)hstate)[b * DD + d]; hr = h.x; hi = h.y; }
  for (int tt = 0; tt < CH; ++tt) {
    const int t = t0 + tt;
    const int id = ids[b * S_LEN + t];
    const float w  = emb[(size_t)id * 512 + d];
    const float bv = emb[(size_t)id * 512 + 256 + d];
    const float wl = 1.f + fabsf(w);
    const float tphi = wrap2pi((float)t * 1.618033988749895f);
    const float thr = hr / wl + bv + tphi;
    const float thi = hi / wl + bv + tphi;
    const float2 a = lut[lut_index(thr)];
    const float2 c = lut[lut_index(thi)];
    hr = a.y * c.y - a.x * c.x;
    hi = a.y * c.x + a.x * c.y;
    union { unsigned int u; _Float16 h2[2]; } pk;
    pk.h2[0] = (_Float16)hr; pk.h2[1] = (_Float16)hi;
    *(((unsigned int*)(X0 + (size_t)(tt * BB + b) * TWO_K)) + d) = pk.u;
  }
  ((float2*)hstate)[b * DD + d] = make_float2(hr, hi);
}

// ---------------- rotation prefix via parallel integer scan ----------------
// One block per (l,n): 256 threads x 4 t each. S_t = prefix sum of LUT indices;
// C[t] = (cos,sin) of (2*pi/4096)*(S_t&4095), D[t] = conj. sincosf(const*idx) is
// bit-identical to the LDS LUT entries used elsewhere (same formula).
__global__ __launch_bounds__(256) void k_rot(const float* __restrict__ omega,
                                             float2* __restrict__ C0, float2* __restrict__ D0,
                                             float2* __restrict__ D1, float2* __restrict__ C1last) {
  const int blk = blockIdx.x;               // 0..2047
  const int l = blk >> 10, n = blk & (NN - 1);
  const int tid = threadIdx.x;
  const int lane = tid & 63;
  const int wid = tid >> 6;
  const float om = omega[l * NN + n];

  int idxv[4], pre[4];
  int own = 0;
  const int tb = tid * 4;
#pragma unroll
  for (int j = 0; j < 4; ++j) {
    idxv[j] = lut_index(om + (float)(tb + j) * 1.618033988749895f);
    own += idxv[j];
    pre[j] = own;                           // inclusive within thread
  }
  // wave-inclusive scan of per-thread sums
  int v = own;
#pragma unroll
  for (int off = 1; off < 64; off <<= 1) {
    int u = __shfl_up(v, off);
    if (lane >= off) v += u;
  }
  __shared__ int wsum[4];
  if (lane == 63) wsum[wid] = v;
  __syncthreads();
  int woff = 0;
#pragma unroll
  for (int w = 0; w < 4; ++w) woff += (w < wid) ? wsum[w] : 0;
  const int excl = woff + v - own;          // exclusive prefix for this thread

#pragma unroll
  for (int j = 0; j < 4; ++j) {
    const int t = tb + j;
    const int idx = (excl + pre[j]) & 4095;
    float s, c;
    __sincosf(0.0015339807878856412f * (float)idx, &s, &c);
    // use precise libm-matching path: recompute with sinf/cosf semantics
    s = sinf(0.0015339807878856412f * (float)idx);
    c = cosf(0.0015339807878856412f * (float)idx);
    if (l == 0) {
      C0[t * NN + n] = make_float2(c, s);
      D0[t * NN + n] = make_float2(c, -s);
    } else {
      D1[t * NN + n] = make_float2(c, -s);
      if (t == S_LEN - 1) C1last[n] = make_float2(c, s);
    }
  }
}

// ---------------- f16 MFMA GEMM: C = A @ BT^T, optional complex rotation epilogue ----------------
// A [M,K] row-major f16, BT [N,K] row-major f16 (i.e. B transposed), C [M,N] f16.
// rot: nullptr or [M/128, N/2] float2; row-block t = blockIdx.y (BM=128=BB so each tile is one t).
__global__ __launch_bounds__(256, 2) void k_gemm(const _Float16* __restrict__ A,
                                                 const _Float16* __restrict__ BT,
                                                 _Float16* __restrict__ C,
                                                 int M, int N, int K,
                                                 const float2* __restrict__ rot) {
  __shared__ __align__(16) _Float16 As[128 * 64];
  __shared__ __align__(16) _Float16 Bs[128 * 64];
  const int tid = threadIdx.x;
  const int lane = tid & 63;
  const int wave = tid >> 6;
  const int wm = wave >> 1;
  const int wn = wave & 1;
  const int m0 = blockIdx.y * 128;
  const int n0 = blockIdx.x * 128;

  const int srow = lane >> 3;               // row within 8-row chunk
  const int schunk = (lane & 7) ^ srow;     // XOR-swizzled source 16B-chunk

  f32x4 acc[4][4] = {};

  for (int kt = 0; kt < K; kt += 64) {
#pragma unroll
    for (int j = 0; j < 4; ++j) {
      const int c = wave * 4 + j;           // chunk 0..15, covers rows c*8..c*8+7
      const int row = c * 8 + srow;
      const _Float16* srcA = A + (size_t)(m0 + row) * K + kt + schunk * 8;
      __builtin_amdgcn_global_load_lds((const __attribute__((address_space(1))) void*)srcA,
                                       (__attribute__((address_space(3))) void*)(As + c * 512), 16, 0, 0);
      const _Float16* srcB = BT + (size_t)(n0 + row) * K + kt + schunk * 8;
      __builtin_amdgcn_global_load_lds((const __attribute__((address_space(1))) void*)srcB,
                                       (__attribute__((address_space(3))) void*)(Bs + c * 512), 16, 0, 0);
    }
    __syncthreads();
#pragma unroll
    for (int ks = 0; ks < 2; ++ks) {
      half8 af[4], bf[4];
#pragma unroll
      for (int mr = 0; mr < 4; ++mr) {
        const int ar = wm * 64 + mr * 16 + (lane & 15);
        const int p = ((ks * 4) + (lane >> 4)) ^ (ar & 7);
        af[mr] = *(const half8*)(As + ar * 64 + p * 8);
      }
#pragma unroll
      for (int nr = 0; nr < 4; ++nr) {
        const int br = wn * 64 + nr * 16 + (lane & 15);
        const int p = ((ks * 4) + (lane >> 4)) ^ (br & 7);
        bf[nr] = *(const half8*)(Bs + br * 64 + p * 8);
      }
#pragma unroll
      for (int mr = 0; mr < 4; ++mr)
#pragma unroll
        for (int nr = 0; nr < 4; ++nr)
          acc[mr][nr] = __builtin_amdgcn_mfma_f32_16x16x32_f16(af[mr], bf[nr], acc[mr][nr], 0, 0, 0);
    }
    __syncthreads();
  }

  const int halfN = N >> 1;
  const int t = blockIdx.y;
#pragma unroll
  for (int mr = 0; mr < 4; ++mr)
#pragma unroll
    for (int nr = 0; nr < 4; ++nr) {
      const int col = n0 + wn * 64 + nr * 16 + (lane & 15);
      const int rbase = m0 + wm * 64 + mr * 16 + ((lane >> 4) << 2);
      float2 dr = make_float2(1.f, 0.f);
      if (rot) dr = rot[(size_t)t * halfN + (col >> 1)];
#pragma unroll
      for (int j = 0; j < 4; ++j) {
        float v = acc[mr][nr][j];
        if (rot) {
          const float pv = __shfl_xor(v, 1);
          v = (lane & 1) ? (dr.x * v + dr.y * pv) : (dr.x * v - dr.y * pv);
        }
        C[(size_t)(rbase + j) * N + col] = (_Float16)v;
      }
    }
}

// ---------------- prefix-sum over t (in place), then multiply by C0[t]; 2 complex/thread ----------------
__global__ __launch_bounds__(256) void k_scan(_Float16* __restrict__ V,          // [CH*BB, TWO_N]
                                              const float2* __restrict__ C0c,    // [CH, NN]
                                              float2* __restrict__ ZS, int CH, int first) {
  const int gid = blockIdx.x * 256 + threadIdx.x;  // b*(NN/2) + npair
  const int npair = gid & (NN / 2 - 1);
  const int b = gid >> 9;
  const int n = npair * 2;
  float zr0, zi0, zr1, zi1;
  if (first) { zr0 = zi0 = zr1 = zi1 = 0.f; }
  else {
    float4 z = *(const float4*)(ZS + (size_t)b * NN + n);
    zr0 = z.x; zi0 = z.y; zr1 = z.z; zi1 = z.w;
  }
  for (int tt = 0; tt < CH; ++tt) {
    uint2* p = (uint2*)(((unsigned int*)(V + (size_t)(tt * BB + b) * TWO_N)) + n);
    uint2 cv = *p;
    union { unsigned int u; _Float16 h2[2]; } a, c;
    a.u = cv.x; c.u = cv.y;
    zr0 += (float)a.h2[0]; zi0 += (float)a.h2[1];
    zr1 += (float)c.h2[0]; zi1 += (float)c.h2[1];
    const float4 cc = *(const float4*)(C0c + (size_t)tt * NN + n);
    a.h2[0] = (_Float16)(cc.x * zr0 - cc.y * zi0);
    a.h2[1] = (_Float16)(cc.x * zi0 + cc.y * zr0);
    c.h2[0] = (_Float16)(cc.z * zr1 - cc.w * zi1);
    c.h2[1] = (_Float16)(cc.z * zi1 + cc.w * zr1);
    *p = make_uint2(a.u, c.u);
  }
  *(float4*)(ZS + (size_t)b * NN + n) = make_float4(zr0, zi0, zr1, zi1);
}

// ---------------- reduce over t: s1[b, n'8] += sum_t U[t,b,n'8], half8 vectorized ----------------
__global__ __launch_bounds__(256) void k_reduce(const _Float16* __restrict__ U,  // [CH*BB, TWO_N]
                                                float* __restrict__ s1, int CH, int first) {
  const int gid = blockIdx.x * 256 + threadIdx.x;  // b*(TWO_N/8) + g
  const int g = gid & (TWO_N / 8 - 1);
  const int b = gid >> 8;
  const int np = g * 8;
  f32x8 acc;
  if (first) {
#pragma unroll
    for (int j = 0; j < 8; ++j) acc[j] = 0.f;
  } else {
    acc = *(const f32x8*)(s1 + (size_t)b * TWO_N + np);
  }
  for (int tt = 0; tt < CH; ++tt) {
    const half8 v = *(const half8*)(U + (size_t)(tt * BB + b) * TWO_N + np);
#pragma unroll
    for (int j = 0; j < 8; ++j) acc[j] += (float)v[j];
  }
  *(f32x8*)(s1 + (size_t)b * TWO_N + np) = acc;
}

// ---------------- s1c = C1last (*) s1 ----------------
__global__ __launch_bounds__(256) void k_s1c(const float* __restrict__ s1,
                                             const float2* __restrict__ C1last,
                                             float* __restrict__ s1c) {
  const int gid = blockIdx.x * 256 + threadIdx.x;  // b*NN + n
  const int n = gid & (NN - 1);
  const int b = gid >> 10;
  const float sr = s1[b * TWO_N + 2 * n], si = s1[b * TWO_N + 2 * n + 1];
  const float2 c = C1last[n];
  s1c[b * TWO_N + 2 * n]     = c.x * sr - c.y * si;
  s1c[b * TWO_N + 2 * n + 1] = c.x * si + c.y * sr;
}

// ---------------- tail GEMM: one wave per output, A [M,K] f32, BT [N,K] f32 ----------------
__global__ __launch_bounds__(256) void k_tail(const float* __restrict__ A,
                                              const float* __restrict__ BT,
                                              float* __restrict__ C, int M, int N, int K) {
  const int wave = threadIdx.x >> 6;
  const int lane = threadIdx.x & 63;
  const int o = blockIdx.x * 4 + wave;     // output index
  if (o >= M * N) return;
  const int row = o / N;
  const int col = o - row * N;
  const float4* __restrict__ a4 = (const float4*)(A + (size_t)row * K);
  const float4* __restrict__ b4 = (const float4*)(BT + (size_t)col * K);
  float acc = 0.f;
  const int nit = K >> 8;                  // K / (64 lanes * 4)
  for (int it = 0; it < nit; ++it) {
    const float4 av = a4[it * 64 + lane];
    const float4 bv = b4[it * 64 + lane];
    acc = fmaf(av.x, bv.x, acc);
    acc = fmaf(av.y, bv.y, acc);
    acc = fmaf(av.z, bv.z, acc);
    acc = fmaf(av.w, bv.w, acc);
  }
#pragma unroll
  for (int s = 32; s >= 1; s >>= 1) acc += __shfl_xor(acc, s);
  if (lane == 0) C[o] = acc;
}

// ---------------- weight packing ----------------
// win (src [DD,NN]) -> BT [TWO_N, TWO_K] f16 (transposed interleaved-complex)
__global__ __launch_bounds__(256) void k_prep_in(const float* __restrict__ r, const float* __restrict__ im,
                                                 _Float16* __restrict__ dst) {
  const int gid = blockIdx.x * 256 + threadIdx.x;  // k*NN + n
  const int n = gid & (NN - 1);
  const int k = gid >> 10;
  const float rv = r[(size_t)k * NN + n], iv = im[(size_t)k * NN + n];
  const size_t base = (size_t)(2 * n) * TWO_K + 2 * k;
  dst[base] = (_Float16)rv;              dst[base + 1] = (_Float16)(-iv);
  dst[base + TWO_K] = (_Float16)iv;      dst[base + TWO_K + 1] = (_Float16)rv;
}
// wout (src [NN,DD]) -> BT [TWO_K, TWO_N] f16
__global__ __launch_bounds__(256) void k_prep_out(const float* __restrict__ r, const float* __restrict__ im,
                                                  _Float16* __restrict__ dst) {
  const int gid = blockIdx.x * 256 + threadIdx.x;  // n*DD + d
  const int d = gid & (DD - 1);
  const int n = gid >> 8;
  const float rv = r[(size_t)n * DD + d], iv = im[(size_t)n * DD + d];
  const size_t base = (size_t)(2 * d) * TWO_N + 2 * n;
  dst[base] = (_Float16)rv;              dst[base + 1] = (_Float16)(-iv);
  dst[base + TWO_N] = (_Float16)iv;      dst[base + TWO_N + 1] = (_Float16)rv;
}
// wout[1] (src [NN,DD]) -> transposed f32 [TWO_K, TWO_N]: WT[j,i] = Wout1[i,j]
__global__ __launch_bounds__(256) void k_prep_wout1T(const float* __restrict__ r, const float* __restrict__ im,
                                                     float* __restrict__ dstT) {
  const int gid = blockIdx.x * 256 + threadIdx.x;  // d*NN + n
  const int n = gid & (NN - 1);
  const int d = gid >> 10;
  const float rv = r[(size_t)n * DD + d], iv = im[(size_t)n * DD + d];
  const size_t b0 = (size_t)(2 * d) * TWO_N + 2 * n;
  const size_t b1 = (size_t)(2 * d + 1) * TWO_N + 2 * n;
  dstT[b0] = rv;     dstT[b0 + 1] = -iv;
  dstT[b1] = iv;     dstT[b1 + 1] = rv;
}
// Wfin transposed f32 [256, TWO_K]: WfinT[s, 2d] = pr+pi ; WfinT[s, 2d+1] = pr-pi
__global__ __launch_bounds__(256) void k_prep_finT(const float* __restrict__ pr, const float* __restrict__ pi_,
                                                   float* __restrict__ dstT) {
  const int gid = blockIdx.x * 256 + threadIdx.x;  // s*DD + d
  const int d = gid & (DD - 1);
  const int s = gid >> 8;
  const float a = pr[(size_t)d * 256 + s], b = pi_[(size_t)d * 256 + s];
  dstT[(size_t)s * TWO_K + 2 * d] = a + b;
  dstT[(size_t)s * TWO_K + 2 * d + 1] = a - b;
}

extern "C" void kernel_launch(void* const* d_in, const int* in_sizes, int n_in,
                              void* d_out, int out_size, void* d_ws, size_t ws_size,
                              hipStream_t stream) {
  const int* ids      = (const int*)d_in[0];
  const float* emb    = (const float*)d_in[1];
  const float* win_r  = (const float*)d_in[2];
  const float* win_i  = (const float*)d_in[3];
  const float* wout_r = (const float*)d_in[4];
  const float* wout_i = (const float*)d_in[5];
  const float* omega  = (const float*)d_in[6];
  const float* outp_r = (const float*)d_in[7];
  const float* outp_i = (const float*)d_in[8];

  char* ws = (char*)d_ws;
  size_t off = 0;
  auto alloc = [&](size_t bytes) { void* p = ws + off; off += (bytes + 255) & ~(size_t)255; return p; };

  float2* C0     = (float2*)alloc((size_t)S_LEN * NN * 8);
  float2* D0     = (float2*)alloc((size_t)S_LEN * NN * 8);
  float2* D1     = (float2*)alloc((size_t)S_LEN * NN * 8);
  float2* C1last = (float2*)alloc((size_t)NN * 8);
  float2* ZS     = (float2*)alloc((size_t)BB * NN * 8);
  float* hstate  = (float*)alloc((size_t)BB * DD * 2 * 4);
  float* s1      = (float*)alloc((size_t)BB * TWO_N * 4);
  float* s1c     = (float*)alloc((size_t)BB * TWO_N * 4);
  float* xt      = (float*)alloc((size_t)BB * TWO_K * 4);
  _Float16* BTin0  = (_Float16*)alloc((size_t)TWO_N * TWO_K * 2);
  _Float16* BTout0 = (_Float16*)alloc((size_t)TWO_K * TWO_N * 2);
  _Float16* BTin1  = (_Float16*)alloc((size_t)TWO_N * TWO_K * 2);
  float* Wout1T = (float*)alloc((size_t)TWO_K * TWO_N * 4);
  float* WfinT  = (float*)alloc((size_t)256 * TWO_K * 4);
  const size_t fixed = off;

  int CH = 1024;
  while (CH > 32) {
    size_t need = fixed + (size_t)CH * BB * 2 * (TWO_K + TWO_N + TWO_K) + 3 * 256;
    if (need <= ws_size) break;
    CH >>= 1;
  }
  _Float16* X0 = (_Float16*)alloc((size_t)CH * BB * TWO_K * 2);
  _Float16* VB = (_Float16*)alloc((size_t)CH * BB * TWO_N * 2);
  _Float16* Yc = (_Float16*)alloc((size_t)CH * BB * TWO_K * 2);

  k_rot<<<2 * NN, 256, 0, stream>>>(omega, C0, D0, D1, C1last);
  k_prep_in<<<DD * NN / 256, 256, 0, stream>>>(win_r, win_i, BTin0);
  k_prep_in<<<DD * NN / 256, 256, 0, stream>>>(win_r + (size_t)DD * NN, win_i + (size_t)DD * NN, BTin1);
  k_prep_out<<<NN * DD / 256, 256, 0, stream>>>(wout_r, wout_i, BTout0);
  k_prep_wout1T<<<NN * DD / 256, 256, 0, stream>>>(wout_r + (size_t)NN * DD, wout_i + (size_t)NN * DD, Wout1T);
  k_prep_finT<<<DD * 256 / 256, 256, 0, stream>>>(outp_r, outp_i, WfinT);

  const int nchunks = S_LEN / CH;
  for (int c = 0; c < nchunks; ++c) {
    const int t0 = c * CH;
    const int M = CH * BB;
    k_h<<<dim3(BB, 4), 64, 0, stream>>>(ids, emb, hstate, X0, t0, CH);
    dim3 g1(TWO_N / 128, M / 128);
    k_gemm<<<g1, 256, 0, stream>>>(X0, BTin0, VB, M, TWO_N, TWO_K, D0 + (size_t)t0 * NN);
    k_scan<<<BB * (NN / 2) / 256, 256, 0, stream>>>(VB, C0 + (size_t)t0 * NN, ZS, CH, c == 0);
    dim3 g2(TWO_K / 128, M / 128);
    k_gemm<<<g2, 256, 0, stream>>>(VB, BTout0, Yc, M, TWO_K, TWO_N, nullptr);
    k_gemm<<<g1, 256, 0, stream>>>(Yc, BTin1, VB, M, TWO_N, TWO_K, D1 + (size_t)t0 * NN);
    k_reduce<<<BB * (TWO_N / 8) / 256, 256, 0, stream>>>(VB, s1, CH, c == 0);
  }

  k_s1c<<<BB * NN / 256, 256, 0, stream>>>(s1, C1last, s1c);
  // xt[128, 512] = s1c[128, 2048] @ Wout1 (via Wout1T [512, 2048])
  k_tail<<<BB * TWO_K / 4, 256, 0, stream>>>(s1c, Wout1T, xt, BB, TWO_K, TWO_N);
  // out[128, 256] = xt[128, 512] @ Wfin (via WfinT [256, 512])
  k_tail<<<BB * 256 / 4, 256, 0, stream>>>(xt, WfinT, (float*)d_out, BB, 256, TWO_K);
}

// Round 5
// 2408.857 us; speedup vs baseline: 1.6019x; 1.1430x over previous
//
#include <hip/hip_runtime.h>

#define S_LEN 1024
#define BB 128
#define DD 256
#define NN 1024
#define TWO_K 512   // 2*DD
#define TWO_N 2048  // 2*NN
#define PF 8

typedef _Float16 half8 __attribute__((ext_vector_type(8)));
typedef float f32x4 __attribute__((ext_vector_type(4)));
typedef float f32x8 __attribute__((ext_vector_type(8)));

__device__ __forceinline__ float wrap2pi(float x) {
  float r = fmodf(x, 6.283185307179586f);
  if (r < 0.f) r += 6.283185307179586f;
  return r;
}
__device__ __forceinline__ int lut_index(float th) {
  float w = wrap2pi(th);
  return ((int)floorf(w * 651.8986469044033f)) & 4095;
}

// ---------------- h recurrence (pointwise over b,d) -> X0 [CH*BB, 2*DD] f16 interleaved ----------------
// Software-pipelined: emb gather (id -> w,bv) is prefetched 1 stage (PF=8 t's) ahead,
// ids 2 stages ahead, so only the LUT/VALU chain remains loop-carried.
__global__ __launch_bounds__(256) void k_h(const int* __restrict__ ids,
                                           const float* __restrict__ emb,
                                           float* __restrict__ hstate,
                                           _Float16* __restrict__ X0,
                                           int t0, int CH) {
  __shared__ __align__(16) float2 lut[4096];
  const int d = threadIdx.x;                 // 0..255
  for (int i = d; i < 4096; i += 256) {
    float ang = 0.0015339807878856412f * (float)i;
    lut[i] = make_float2(sinf(ang), cosf(ang));
  }
  __syncthreads();
  const int b = blockIdx.x;
  float hr, hi;
  if (t0 == 0) { hr = 0.f; hi = 0.f; }
  else { float2 h = ((const float2*)hstate)[b * DD + d]; hr = h.x; hi = h.y; }

  const int* __restrict__ idrow = ids + b * S_LEN + t0;
  const int NST = CH / PF;

  int idn[PF];
  float wc[PF], bc[PF], wn[PF], bn[PF];
  {
    int id0[PF];
#pragma unroll
    for (int j = 0; j < PF; ++j) id0[j] = idrow[j];
#pragma unroll
    for (int j = 0; j < PF; ++j) {
      const float* e = emb + (size_t)id0[j] * 512;
      wc[j] = e[d]; bc[j] = e[256 + d];
    }
  }
#pragma unroll
  for (int j = 0; j < PF; ++j) idn[j] = idrow[PF + j];

  for (int st = 0; st < NST; ++st) {
    // prefetch emb for stage st+1 (ids already in idn)
    if (st + 1 < NST) {
#pragma unroll
      for (int j = 0; j < PF; ++j) {
        const float* e = emb + (size_t)idn[j] * 512;
        wn[j] = e[d]; bn[j] = e[256 + d];
      }
    }
    // compute stage st (loop-carried h chain; data already in registers)
#pragma unroll
    for (int j = 0; j < PF; ++j) {
      const int tt = st * PF + j;
      const int t = t0 + tt;
      const float wl = 1.f + fabsf(wc[j]);
      const float tphi = wrap2pi((float)t * 1.618033988749895f);
      const float thr = hr / wl + bc[j] + tphi;
      const float thi = hi / wl + bc[j] + tphi;
      const float2 a = lut[lut_index(thr)];
      const float2 c = lut[lut_index(thi)];
      hr = a.y * c.y - a.x * c.x;
      hi = a.y * c.x + a.x * c.y;
      union { unsigned int u; _Float16 h2[2]; } pk;
      pk.h2[0] = (_Float16)hr; pk.h2[1] = (_Float16)hi;
      *(((unsigned int*)(X0 + (size_t)(tt * BB + b) * TWO_K)) + d) = pk.u;
    }
    // rotate prefetch registers; fetch ids for stage st+2
#pragma unroll
    for (int j = 0; j < PF; ++j) { wc[j] = wn[j]; bc[j] = bn[j]; }
    if (st + 2 < NST) {
#pragma unroll
      for (int j = 0; j < PF; ++j) idn[j] = idrow[(st + 2) * PF + j];
    }
  }
  ((float2*)hstate)[b * DD + d] = make_float2(hr, hi);
}

// ---------------- rotation prefix via parallel integer scan ----------------
__global__ __launch_bounds__(256) void k_rot(const float* __restrict__ omega,
                                             float2* __restrict__ C0, float2* __restrict__ D0,
                                             float2* __restrict__ D1, float2* __restrict__ C1last) {
  const int blk = blockIdx.x;               // 0..2047
  const int l = blk >> 10, n = blk & (NN - 1);
  const int tid = threadIdx.x;
  const int lane = tid & 63;
  const int wid = tid >> 6;
  const float om = omega[l * NN + n];

  int pre[4];
  int own = 0;
  const int tb = tid * 4;
#pragma unroll
  for (int j = 0; j < 4; ++j) {
    own += lut_index(om + (float)(tb + j) * 1.618033988749895f);
    pre[j] = own;                           // inclusive within thread
  }
  int v = own;
#pragma unroll
  for (int off = 1; off < 64; off <<= 1) {
    int u = __shfl_up(v, off);
    if (lane >= off) v += u;
  }
  __shared__ int wsum[4];
  if (lane == 63) wsum[wid] = v;
  __syncthreads();
  int woff = 0;
#pragma unroll
  for (int w = 0; w < 4; ++w) woff += (w < wid) ? wsum[w] : 0;
  const int excl = woff + v - own;

#pragma unroll
  for (int j = 0; j < 4; ++j) {
    const int t = tb + j;
    const int idx = (excl + pre[j]) & 4095;
    const float s = sinf(0.0015339807878856412f * (float)idx);
    const float c = cosf(0.0015339807878856412f * (float)idx);
    if (l == 0) {
      C0[t * NN + n] = make_float2(c, s);
      D0[t * NN + n] = make_float2(c, -s);
    } else {
      D1[t * NN + n] = make_float2(c, -s);
      if (t == S_LEN - 1) C1last[n] = make_float2(c, s);
    }
  }
}

// ---------------- f16 MFMA GEMM: C = A @ BT^T, optional complex rotation epilogue ----------------
__global__ __launch_bounds__(256, 2) void k_gemm(const _Float16* __restrict__ A,
                                                 const _Float16* __restrict__ BT,
                                                 _Float16* __restrict__ C,
                                                 int M, int N, int K,
                                                 const float2* __restrict__ rot) {
  __shared__ __align__(16) _Float16 As[128 * 64];
  __shared__ __align__(16) _Float16 Bs[128 * 64];
  const int tid = threadIdx.x;
  const int lane = tid & 63;
  const int wave = tid >> 6;
  const int wm = wave >> 1;
  const int wn = wave & 1;
  const int m0 = blockIdx.y * 128;
  const int n0 = blockIdx.x * 128;

  const int srow = lane >> 3;               // row within 8-row chunk
  const int schunk = (lane & 7) ^ srow;     // XOR-swizzled source 16B-chunk

  f32x4 acc[4][4] = {};

  for (int kt = 0; kt < K; kt += 64) {
#pragma unroll
    for (int j = 0; j < 4; ++j) {
      const int c = wave * 4 + j;           // chunk 0..15, covers rows c*8..c*8+7
      const int row = c * 8 + srow;
      const _Float16* srcA = A + (size_t)(m0 + row) * K + kt + schunk * 8;
      __builtin_amdgcn_global_load_lds((const __attribute__((address_space(1))) void*)srcA,
                                       (__attribute__((address_space(3))) void*)(As + c * 512), 16, 0, 0);
      const _Float16* srcB = BT + (size_t)(n0 + row) * K + kt + schunk * 8;
      __builtin_amdgcn_global_load_lds((const __attribute__((address_space(1))) void*)srcB,
                                       (__attribute__((address_space(3))) void*)(Bs + c * 512), 16, 0, 0);
    }
    __syncthreads();
#pragma unroll
    for (int ks = 0; ks < 2; ++ks) {
      half8 af[4], bf[4];
#pragma unroll
      for (int mr = 0; mr < 4; ++mr) {
        const int ar = wm * 64 + mr * 16 + (lane & 15);
        const int p = ((ks * 4) + (lane >> 4)) ^ (ar & 7);
        af[mr] = *(const half8*)(As + ar * 64 + p * 8);
      }
#pragma unroll
      for (int nr = 0; nr < 4; ++nr) {
        const int br = wn * 64 + nr * 16 + (lane & 15);
        const int p = ((ks * 4) + (lane >> 4)) ^ (br & 7);
        bf[nr] = *(const half8*)(Bs + br * 64 + p * 8);
      }
#pragma unroll
      for (int mr = 0; mr < 4; ++mr)
#pragma unroll
        for (int nr = 0; nr < 4; ++nr)
          acc[mr][nr] = __builtin_amdgcn_mfma_f32_16x16x32_f16(af[mr], bf[nr], acc[mr][nr], 0, 0, 0);
    }
    __syncthreads();
  }

  const int halfN = N >> 1;
  const int t = blockIdx.y;
#pragma unroll
  for (int mr = 0; mr < 4; ++mr)
#pragma unroll
    for (int nr = 0; nr < 4; ++nr) {
      const int col = n0 + wn * 64 + nr * 16 + (lane & 15);
      const int rbase = m0 + wm * 64 + mr * 16 + ((lane >> 4) << 2);
      float2 dr = make_float2(1.f, 0.f);
      if (rot) dr = rot[(size_t)t * halfN + (col >> 1)];
#pragma unroll
      for (int j = 0; j < 4; ++j) {
        float v = acc[mr][nr][j];
        if (rot) {
          const float pv = __shfl_xor(v, 1);
          v = (lane & 1) ? (dr.x * v + dr.y * pv) : (dr.x * v - dr.y * pv);
        }
        C[(size_t)(rbase + j) * N + col] = (_Float16)v;
      }
    }
}

// ---------------- prefix-sum over t (in place), then multiply by C0[t]; 2 complex/thread ----------------
__global__ __launch_bounds__(256) void k_scan(_Float16* __restrict__ V,          // [CH*BB, TWO_N]
                                              const float2* __restrict__ C0c,    // [CH, NN]
                                              float2* __restrict__ ZS, int CH, int first) {
  const int gid = blockIdx.x * 256 + threadIdx.x;  // b*(NN/2) + npair
  const int npair = gid & (NN / 2 - 1);
  const int b = gid >> 9;
  const int n = npair * 2;
  float zr0, zi0, zr1, zi1;
  if (first) { zr0 = zi0 = zr1 = zi1 = 0.f; }
  else {
    float4 z = *(const float4*)(ZS + (size_t)b * NN + n);
    zr0 = z.x; zi0 = z.y; zr1 = z.z; zi1 = z.w;
  }
  for (int tt = 0; tt < CH; ++tt) {
    uint2* p = (uint2*)(((unsigned int*)(V + (size_t)(tt * BB + b) * TWO_N)) + n);
    uint2 cv = *p;
    union { unsigned int u; _Float16 h2[2]; } a, c;
    a.u = cv.x; c.u = cv.y;
    zr0 += (float)a.h2[0]; zi0 += (float)a.h2[1];
    zr1 += (float)c.h2[0]; zi1 += (float)c.h2[1];
    const float4 cc = *(const float4*)(C0c + (size_t)tt * NN + n);
    a.h2[0] = (_Float16)(cc.x * zr0 - cc.y * zi0);
    a.h2[1] = (_Float16)(cc.x * zi0 + cc.y * zr0);
    c.h2[0] = (_Float16)(cc.z * zr1 - cc.w * zi1);
    c.h2[1] = (_Float16)(cc.z * zi1 + cc.w * zr1);
    *p = make_uint2(a.u, c.u);
  }
  *(float4*)(ZS + (size_t)b * NN + n) = make_float4(zr0, zi0, zr1, zi1);
}

// ---------------- reduce over t: s1[b, n'8] += sum_t U[t,b,n'8], half8 vectorized ----------------
__global__ __launch_bounds__(256) void k_reduce(const _Float16* __restrict__ U,  // [CH*BB, TWO_N]
                                                float* __restrict__ s1, int CH, int first) {
  const int gid = blockIdx.x * 256 + threadIdx.x;  // b*(TWO_N/8) + g
  const int g = gid & (TWO_N / 8 - 1);
  const int b = gid >> 8;
  const int np = g * 8;
  f32x8 acc;
  if (first) {
#pragma unroll
    for (int j = 0; j < 8; ++j) acc[j] = 0.f;
  } else {
    acc = *(const f32x8*)(s1 + (size_t)b * TWO_N + np);
  }
  for (int tt = 0; tt < CH; ++tt) {
    const half8 v = *(const half8*)(U + (size_t)(tt * BB + b) * TWO_N + np);
#pragma unroll
    for (int j = 0; j < 8; ++j) acc[j] += (float)v[j];
  }
  *(f32x8*)(s1 + (size_t)b * TWO_N + np) = acc;
}

// ---------------- s1c = C1last (*) s1 ----------------
__global__ __launch_bounds__(256) void k_s1c(const float* __restrict__ s1,
                                             const float2* __restrict__ C1last,
                                             float* __restrict__ s1c) {
  const int gid = blockIdx.x * 256 + threadIdx.x;  // b*NN + n
  const int n = gid & (NN - 1);
  const int b = gid >> 10;
  const float sr = s1[b * TWO_N + 2 * n], si = s1[b * TWO_N + 2 * n + 1];
  const float2 c = C1last[n];
  s1c[b * TWO_N + 2 * n]     = c.x * sr - c.y * si;
  s1c[b * TWO_N + 2 * n + 1] = c.x * si + c.y * sr;
}

// ---------------- tail GEMM: one wave per output, A [M,K] f32, BT [N,K] f32 ----------------
__global__ __launch_bounds__(256) void k_tail(const float* __restrict__ A,
                                              const float* __restrict__ BT,
                                              float* __restrict__ C, int M, int N, int K) {
  const int wave = threadIdx.x >> 6;
  const int lane = threadIdx.x & 63;
  const int o = blockIdx.x * 4 + wave;     // output index
  if (o >= M * N) return;
  const int row = o / N;
  const int col = o - row * N;
  const float4* __restrict__ a4 = (const float4*)(A + (size_t)row * K);
  const float4* __restrict__ b4 = (const float4*)(BT + (size_t)col * K);
  float acc = 0.f;
  const int nit = K >> 8;                  // K / (64 lanes * 4)
  for (int it = 0; it < nit; ++it) {
    const float4 av = a4[it * 64 + lane];
    const float4 bv = b4[it * 64 + lane];
    acc = fmaf(av.x, bv.x, acc);
    acc = fmaf(av.y, bv.y, acc);
    acc = fmaf(av.z, bv.z, acc);
    acc = fmaf(av.w, bv.w, acc);
  }
#pragma unroll
  for (int s = 32; s >= 1; s >>= 1) acc += __shfl_xor(acc, s);
  if (lane == 0) C[o] = acc;
}

// ---------------- weight packing ----------------
__global__ __launch_bounds__(256) void k_prep_in(const float* __restrict__ r, const float* __restrict__ im,
                                                 _Float16* __restrict__ dst) {
  const int gid = blockIdx.x * 256 + threadIdx.x;  // k*NN + n
  const int n = gid & (NN - 1);
  const int k = gid >> 10;
  const float rv = r[(size_t)k * NN + n], iv = im[(size_t)k * NN + n];
  const size_t base = (size_t)(2 * n) * TWO_K + 2 * k;
  dst[base] = (_Float16)rv;              dst[base + 1] = (_Float16)(-iv);
  dst[base + TWO_K] = (_Float16)iv;      dst[base + TWO_K + 1] = (_Float16)rv;
}
__global__ __launch_bounds__(256) void k_prep_out(const float* __restrict__ r, const float* __restrict__ im,
                                                  _Float16* __restrict__ dst) {
  const int gid = blockIdx.x * 256 + threadIdx.x;  // n*DD + d
  const int d = gid & (DD - 1);
  const int n = gid >> 8;
  const float rv = r[(size_t)n * DD + d], iv = im[(size_t)n * DD + d];
  const size_t base = (size_t)(2 * d) * TWO_N + 2 * n;
  dst[base] = (_Float16)rv;              dst[base + 1] = (_Float16)(-iv);
  dst[base + TWO_N] = (_Float16)iv;      dst[base + TWO_N + 1] = (_Float16)rv;
}
__global__ __launch_bounds__(256) void k_prep_wout1T(const float* __restrict__ r, const float* __restrict__ im,
                                                     float* __restrict__ dstT) {
  const int gid = blockIdx.x * 256 + threadIdx.x;  // d*NN + n
  const int n = gid & (NN - 1);
  const int d = gid >> 10;
  const float rv = r[(size_t)n * DD + d], iv = im[(size_t)n * DD + d];
  const size_t b0 = (size_t)(2 * d) * TWO_N + 2 * n;
  const size_t b1 = (size_t)(2 * d + 1) * TWO_N + 2 * n;
  dstT[b0] = rv;     dstT[b0 + 1] = -iv;
  dstT[b1] = iv;     dstT[b1 + 1] = rv;
}
__global__ __launch_bounds__(256) void k_prep_finT(const float* __restrict__ pr, const float* __restrict__ pi_,
                                                   float* __restrict__ dstT) {
  const int gid = blockIdx.x * 256 + threadIdx.x;  // s*DD + d
  const int d = gid & (DD - 1);
  const int s = gid >> 8;
  const float a = pr[(size_t)d * 256 + s], b = pi_[(size_t)d * 256 + s];
  dstT[(size_t)s * TWO_K + 2 * d] = a + b;
  dstT[(size_t)s * TWO_K + 2 * d + 1] = a - b;
}

extern "C" void kernel_launch(void* const* d_in, const int* in_sizes, int n_in,
                              void* d_out, int out_size, void* d_ws, size_t ws_size,
                              hipStream_t stream) {
  const int* ids      = (const int*)d_in[0];
  const float* emb    = (const float*)d_in[1];
  const float* win_r  = (const float*)d_in[2];
  const float* win_i  = (const float*)d_in[3];
  const float* wout_r = (const float*)d_in[4];
  const float* wout_i = (const float*)d_in[5];
  const float* omega  = (const float*)d_in[6];
  const float* outp_r = (const float*)d_in[7];
  const float* outp_i = (const float*)d_in[8];

  char* ws = (char*)d_ws;
  size_t off = 0;
  auto alloc = [&](size_t bytes) { void* p = ws + off; off += (bytes + 255) & ~(size_t)255; return p; };

  float2* C0     = (float2*)alloc((size_t)S_LEN * NN * 8);
  float2* D0     = (float2*)alloc((size_t)S_LEN * NN * 8);
  float2* D1     = (float2*)alloc((size_t)S_LEN * NN * 8);
  float2* C1last = (float2*)alloc((size_t)NN * 8);
  float2* ZS     = (float2*)alloc((size_t)BB * NN * 8);
  float* hstate  = (float*)alloc((size_t)BB * DD * 2 * 4);
  float* s1      = (float*)alloc((size_t)BB * TWO_N * 4);
  float* s1c     = (float*)alloc((size_t)BB * TWO_N * 4);
  float* xt      = (float*)alloc((size_t)BB * TWO_K * 4);
  _Float16* BTin0  = (_Float16*)alloc((size_t)TWO_N * TWO_K * 2);
  _Float16* BTout0 = (_Float16*)alloc((size_t)TWO_K * TWO_N * 2);
  _Float16* BTin1  = (_Float16*)alloc((size_t)TWO_N * TWO_K * 2);
  float* Wout1T = (float*)alloc((size_t)TWO_K * TWO_N * 4);
  float* WfinT  = (float*)alloc((size_t)256 * TWO_K * 4);
  const size_t fixed = off;

  // per-chunk buffers: X0 [CH*BB, TWO_K] f16, VB [CH*BB, TWO_N] f16; Yc aliases X0
  // (X0 is dead after GEMM1, Yc is produced by GEMM2 from VB).
  int CH = 1024;
  while (CH > 32) {
    size_t need = fixed + (size_t)CH * BB * 2 * (TWO_K + TWO_N) + 2 * 256;
    if (need <= ws_size) break;
    CH >>= 1;
  }
  _Float16* X0 = (_Float16*)alloc((size_t)CH * BB * TWO_K * 2);
  _Float16* VB = (_Float16*)alloc((size_t)CH * BB * TWO_N * 2);
  _Float16* Yc = X0;

  k_rot<<<2 * NN, 256, 0, stream>>>(omega, C0, D0, D1, C1last);
  k_prep_in<<<DD * NN / 256, 256, 0, stream>>>(win_r, win_i, BTin0);
  k_prep_in<<<DD * NN / 256, 256, 0, stream>>>(win_r + (size_t)DD * NN, win_i + (size_t)DD * NN, BTin1);
  k_prep_out<<<NN * DD / 256, 256, 0, stream>>>(wout_r, wout_i, BTout0);
  k_prep_wout1T<<<NN * DD / 256, 256, 0, stream>>>(wout_r + (size_t)NN * DD, wout_i + (size_t)NN * DD, Wout1T);
  k_prep_finT<<<DD * 256 / 256, 256, 0, stream>>>(outp_r, outp_i, WfinT);

  const int nchunks = S_LEN / CH;
  for (int c = 0; c < nchunks; ++c) {
    const int t0 = c * CH;
    const int M = CH * BB;
    k_h<<<BB, 256, 0, stream>>>(ids, emb, hstate, X0, t0, CH);
    dim3 g1(TWO_N / 128, M / 128);
    k_gemm<<<g1, 256, 0, stream>>>(X0, BTin0, VB, M, TWO_N, TWO_K, D0 + (size_t)t0 * NN);
    k_scan<<<BB * (NN / 2) / 256, 256, 0, stream>>>(VB, C0 + (size_t)t0 * NN, ZS, CH, c == 0);
    dim3 g2(TWO_K / 128, M / 128);
    k_gemm<<<g2, 256, 0, stream>>>(VB, BTout0, Yc, M, TWO_K, TWO_N, nullptr);
    k_gemm<<<g1, 256, 0, stream>>>(Yc, BTin1, VB, M, TWO_N, TWO_K, D1 + (size_t)t0 * NN);
    k_reduce<<<BB * (TWO_N / 8) / 256, 256, 0, stream>>>(VB, s1, CH, c == 0);
  }

  k_s1c<<<BB * NN / 256, 256, 0, stream>>>(s1, C1last, s1c);
  // xt[128, 512] = s1c[128, 2048] @ Wout1 (via Wout1T [512, 2048])
  k_tail<<<BB * TWO_K / 4, 256, 0, stream>>>(s1c, Wout1T, xt, BB, TWO_K, TWO_N);
  // out[128, 256] = xt[128, 512] @ Wfin (via WfinT [256, 512])
  k_tail<<<BB * 256 / 4, 256, 0, stream>>>(xt, WfinT, (float*)d_out, BB, 256, TWO_K);
}

// Round 6
// 2023.854 us; speedup vs baseline: 1.9067x; 1.1902x over previous
//
#include <hip/hip_runtime.h>

#define S_LEN 1024
#define BB 128
#define DD 256
#define NN 1024
#define TWO_K 512   // 2*DD
#define TWO_N 2048  // 2*NN
#define PF 8

typedef _Float16 half8 __attribute__((ext_vector_type(8)));
typedef _Float16 half4 __attribute__((ext_vector_type(4)));
typedef float f32x4 __attribute__((ext_vector_type(4)));
typedef float f32x8 __attribute__((ext_vector_type(8)));

__device__ __forceinline__ float wrap2pi(float x) {
  float r = fmodf(x, 6.283185307179586f);
  if (r < 0.f) r += 6.283185307179586f;
  return r;
}
__device__ __forceinline__ int lut_index(float th) {
  float w = wrap2pi(th);
  return ((int)floorf(w * 651.8986469044033f)) & 4095;
}

// ---------------- h recurrence (pointwise over b,d) -> X0 [CH*BB, 2*DD] f16 interleaved ----------------
// Software-pipelined: emb gather (id -> w,bv) is prefetched 1 stage (PF=8 t's) ahead,
// ids 2 stages ahead, so only the LUT/VALU chain remains loop-carried.
__global__ __launch_bounds__(256) void k_h(const int* __restrict__ ids,
                                           const float* __restrict__ emb,
                                           float* __restrict__ hstate,
                                           _Float16* __restrict__ X0,
                                           int t0, int CH) {
  __shared__ __align__(16) float2 lut[4096];
  const int d = threadIdx.x;                 // 0..255
  for (int i = d; i < 4096; i += 256) {
    float ang = 0.0015339807878856412f * (float)i;
    lut[i] = make_float2(sinf(ang), cosf(ang));
  }
  __syncthreads();
  const int b = blockIdx.x;
  float hr, hi;
  if (t0 == 0) { hr = 0.f; hi = 0.f; }
  else { float2 h = ((const float2*)hstate)[b * DD + d]; hr = h.x; hi = h.y; }

  const int* __restrict__ idrow = ids + b * S_LEN + t0;
  const int NST = CH / PF;

  int idn[PF];
  float wc[PF], bc[PF], wn[PF], bn[PF];
  {
    int id0[PF];
#pragma unroll
    for (int j = 0; j < PF; ++j) id0[j] = idrow[j];
#pragma unroll
    for (int j = 0; j < PF; ++j) {
      const float* e = emb + (size_t)id0[j] * 512;
      wc[j] = e[d]; bc[j] = e[256 + d];
    }
  }
#pragma unroll
  for (int j = 0; j < PF; ++j) idn[j] = idrow[PF + j];

  for (int st = 0; st < NST; ++st) {
    if (st + 1 < NST) {
#pragma unroll
      for (int j = 0; j < PF; ++j) {
        const float* e = emb + (size_t)idn[j] * 512;
        wn[j] = e[d]; bn[j] = e[256 + d];
      }
    }
#pragma unroll
    for (int j = 0; j < PF; ++j) {
      const int tt = st * PF + j;
      const int t = t0 + tt;
      const float wl = 1.f + fabsf(wc[j]);
      const float tphi = wrap2pi((float)t * 1.618033988749895f);
      const float thr = hr / wl + bc[j] + tphi;
      const float thi = hi / wl + bc[j] + tphi;
      const float2 a = lut[lut_index(thr)];
      const float2 c = lut[lut_index(thi)];
      hr = a.y * c.y - a.x * c.x;
      hi = a.y * c.x + a.x * c.y;
      union { unsigned int u; _Float16 h2[2]; } pk;
      pk.h2[0] = (_Float16)hr; pk.h2[1] = (_Float16)hi;
      *(((unsigned int*)(X0 + (size_t)(tt * BB + b) * TWO_K)) + d) = pk.u;
    }
#pragma unroll
    for (int j = 0; j < PF; ++j) { wc[j] = wn[j]; bc[j] = bn[j]; }
    if (st + 2 < NST) {
#pragma unroll
      for (int j = 0; j < PF; ++j) idn[j] = idrow[(st + 2) * PF + j];
    }
  }
  ((float2*)hstate)[b * DD + d] = make_float2(hr, hi);
}

// ---------------- rotation prefix via parallel integer scan ----------------
__global__ __launch_bounds__(256) void k_rot(const float* __restrict__ omega,
                                             float2* __restrict__ C0, float2* __restrict__ D0,
                                             float2* __restrict__ D1, float2* __restrict__ C1last) {
  const int blk = blockIdx.x;               // 0..2047
  const int l = blk >> 10, n = blk & (NN - 1);
  const int tid = threadIdx.x;
  const int lane = tid & 63;
  const int wid = tid >> 6;
  const float om = omega[l * NN + n];

  int pre[4];
  int own = 0;
  const int tb = tid * 4;
#pragma unroll
  for (int j = 0; j < 4; ++j) {
    own += lut_index(om + (float)(tb + j) * 1.618033988749895f);
    pre[j] = own;
  }
  int v = own;
#pragma unroll
  for (int off = 1; off < 64; off <<= 1) {
    int u = __shfl_up(v, off);
    if (lane >= off) v += u;
  }
  __shared__ int wsum[4];
  if (lane == 63) wsum[wid] = v;
  __syncthreads();
  int woff = 0;
#pragma unroll
  for (int w = 0; w < 4; ++w) woff += (w < wid) ? wsum[w] : 0;
  const int excl = woff + v - own;

#pragma unroll
  for (int j = 0; j < 4; ++j) {
    const int t = tb + j;
    const int idx = (excl + pre[j]) & 4095;
    const float s = sinf(0.0015339807878856412f * (float)idx);
    const float c = cosf(0.0015339807878856412f * (float)idx);
    if (l == 0) {
      C0[t * NN + n] = make_float2(c, s);
      D0[t * NN + n] = make_float2(c, -s);
    } else {
      D1[t * NN + n] = make_float2(c, -s);
      if (t == S_LEN - 1) C1last[n] = make_float2(c, s);
    }
  }
}

// ---------------- f16 MFMA GEMM: C = A @ BT^T, optional complex rotation epilogue ----------------
__global__ __launch_bounds__(256, 2) void k_gemm(const _Float16* __restrict__ A,
                                                 const _Float16* __restrict__ BT,
                                                 _Float16* __restrict__ C,
                                                 int M, int N, int K,
                                                 const float2* __restrict__ rot) {
  __shared__ __align__(16) _Float16 As[128 * 64];
  __shared__ __align__(16) _Float16 Bs[128 * 64];
  const int tid = threadIdx.x;
  const int lane = tid & 63;
  const int wave = tid >> 6;
  const int wm = wave >> 1;
  const int wn = wave & 1;
  const int m0 = blockIdx.y * 128;
  const int n0 = blockIdx.x * 128;

  const int srow = lane >> 3;               // row within 8-row chunk
  const int schunk = (lane & 7) ^ srow;     // XOR-swizzled source 16B-chunk

  f32x4 acc[4][4] = {};

  for (int kt = 0; kt < K; kt += 64) {
#pragma unroll
    for (int j = 0; j < 4; ++j) {
      const int c = wave * 4 + j;           // chunk 0..15, covers rows c*8..c*8+7
      const int row = c * 8 + srow;
      const _Float16* srcA = A + (size_t)(m0 + row) * K + kt + schunk * 8;
      __builtin_amdgcn_global_load_lds((const __attribute__((address_space(1))) void*)srcA,
                                       (__attribute__((address_space(3))) void*)(As + c * 512), 16, 0, 0);
      const _Float16* srcB = BT + (size_t)(n0 + row) * K + kt + schunk * 8;
      __builtin_amdgcn_global_load_lds((const __attribute__((address_space(1))) void*)srcB,
                                       (__attribute__((address_space(3))) void*)(Bs + c * 512), 16, 0, 0);
    }
    __syncthreads();
#pragma unroll
    for (int ks = 0; ks < 2; ++ks) {
      half8 af[4], bf[4];
#pragma unroll
      for (int mr = 0; mr < 4; ++mr) {
        const int ar = wm * 64 + mr * 16 + (lane & 15);
        const int p = ((ks * 4) + (lane >> 4)) ^ (ar & 7);
        af[mr] = *(const half8*)(As + ar * 64 + p * 8);
      }
#pragma unroll
      for (int nr = 0; nr < 4; ++nr) {
        const int br = wn * 64 + nr * 16 + (lane & 15);
        const int p = ((ks * 4) + (lane >> 4)) ^ (br & 7);
        bf[nr] = *(const half8*)(Bs + br * 64 + p * 8);
      }
#pragma unroll
      for (int mr = 0; mr < 4; ++mr)
#pragma unroll
        for (int nr = 0; nr < 4; ++nr)
          acc[mr][nr] = __builtin_amdgcn_mfma_f32_16x16x32_f16(af[mr], bf[nr], acc[mr][nr], 0, 0, 0);
    }
    __syncthreads();
  }

  const int halfN = N >> 1;
  const int t = blockIdx.y;
#pragma unroll
  for (int mr = 0; mr < 4; ++mr)
#pragma unroll
    for (int nr = 0; nr < 4; ++nr) {
      const int col = n0 + wn * 64 + nr * 16 + (lane & 15);
      const int rbase = m0 + wm * 64 + mr * 16 + ((lane >> 4) << 2);
      float2 dr = make_float2(1.f, 0.f);
      if (rot) dr = rot[(size_t)t * halfN + (col >> 1)];
#pragma unroll
      for (int j = 0; j < 4; ++j) {
        float v = acc[mr][nr][j];
        if (rot) {
          const float pv = __shfl_xor(v, 1);
          v = (lane & 1) ? (dr.x * v + dr.y * pv) : (dr.x * v - dr.y * pv);
        }
        C[(size_t)(rbase + j) * N + col] = (_Float16)v;
      }
    }
}

// ---------------- prefix-sum over t (in place), then multiply by C0[t] ----------------
// 2 complex/thread, unroll-8 with register double-buffered prefetch (latency cover).
#define SUF 8
__global__ __launch_bounds__(256) void k_scan(_Float16* __restrict__ V,          // [CH*BB, TWO_N]
                                              const float2* __restrict__ C0c,    // [CH, NN]
                                              float2* __restrict__ ZS, int CH, int first) {
  const int gid = blockIdx.x * 256 + threadIdx.x;  // b*(NN/2) + npair
  const int npair = gid & (NN / 2 - 1);
  const int b = gid >> 9;
  const int n = npair * 2;
  float zr0, zi0, zr1, zi1;
  if (first) { zr0 = zi0 = zr1 = zi1 = 0.f; }
  else {
    float4 z = *(const float4*)(ZS + (size_t)b * NN + n);
    zr0 = z.x; zi0 = z.y; zr1 = z.z; zi1 = z.w;
  }
  uint2 vb[SUF], vn[SUF];
  float4 cb[SUF], cn[SUF];
#pragma unroll
  for (int j = 0; j < SUF; ++j) {
    vb[j] = *(const uint2*)(((const unsigned int*)(V + (size_t)(j * BB + b) * TWO_N)) + n);
    cb[j] = *(const float4*)(C0c + (size_t)j * NN + n);
  }
  for (int st = 0; st < CH; st += SUF) {
    const bool more = (st + SUF) < CH;
    if (more) {
#pragma unroll
      for (int j = 0; j < SUF; ++j) {
        vn[j] = *(const uint2*)(((const unsigned int*)(V + (size_t)((st + SUF + j) * BB + b) * TWO_N)) + n);
        cn[j] = *(const float4*)(C0c + (size_t)(st + SUF + j) * NN + n);
      }
    }
#pragma unroll
    for (int j = 0; j < SUF; ++j) {
      union { unsigned int u; _Float16 h2[2]; } a, c;
      a.u = vb[j].x; c.u = vb[j].y;
      zr0 += (float)a.h2[0]; zi0 += (float)a.h2[1];
      zr1 += (float)c.h2[0]; zi1 += (float)c.h2[1];
      const float4 cc = cb[j];
      a.h2[0] = (_Float16)(cc.x * zr0 - cc.y * zi0);
      a.h2[1] = (_Float16)(cc.x * zi0 + cc.y * zr0);
      c.h2[0] = (_Float16)(cc.z * zr1 - cc.w * zi1);
      c.h2[1] = (_Float16)(cc.z * zi1 + cc.w * zr1);
      *(uint2*)(((unsigned int*)(V + (size_t)((st + j) * BB + b) * TWO_N)) + n) = make_uint2(a.u, c.u);
    }
#pragma unroll
    for (int j = 0; j < SUF; ++j) { vb[j] = vn[j]; cb[j] = cn[j]; }
  }
  *(float4*)(ZS + (size_t)b * NN + n) = make_float4(zr0, zi0, zr1, zi1);
}

// ---------------- reduce over t: s1[b, np4] += sum_t U[t,b,np4] ----------------
// 4 halves/thread (65536 threads), unroll-8 register double-buffered prefetch.
__global__ __launch_bounds__(256) void k_reduce(const _Float16* __restrict__ U,  // [CH*BB, TWO_N]
                                                float* __restrict__ s1, int CH, int first) {
  const int gid = blockIdx.x * 256 + threadIdx.x;  // b*(TWO_N/4) + g
  const int g = gid & (TWO_N / 4 - 1);
  const int b = gid >> 9;
  const int np = g * 4;
  f32x4 acc;
  if (first) {
#pragma unroll
    for (int j = 0; j < 4; ++j) acc[j] = 0.f;
  } else {
    acc = *(const f32x4*)(s1 + (size_t)b * TWO_N + np);
  }
  half4 vb[SUF], vn[SUF];
#pragma unroll
  for (int j = 0; j < SUF; ++j)
    vb[j] = *(const half4*)(U + (size_t)(j * BB + b) * TWO_N + np);
  for (int st = 0; st < CH; st += SUF) {
    const bool more = (st + SUF) < CH;
    if (more) {
#pragma unroll
      for (int j = 0; j < SUF; ++j)
        vn[j] = *(const half4*)(U + (size_t)((st + SUF + j) * BB + b) * TWO_N + np);
    }
#pragma unroll
    for (int j = 0; j < SUF; ++j) {
#pragma unroll
      for (int q = 0; q < 4; ++q) acc[q] += (float)vb[j][q];
    }
#pragma unroll
    for (int j = 0; j < SUF; ++j) vb[j] = vn[j];
  }
  *(f32x4*)(s1 + (size_t)b * TWO_N + np) = acc;
}

// ---------------- s1c = C1last (*) s1 ----------------
__global__ __launch_bounds__(256) void k_s1c(const float* __restrict__ s1,
                                             const float2* __restrict__ C1last,
                                             float* __restrict__ s1c) {
  const int gid = blockIdx.x * 256 + threadIdx.x;  // b*NN + n
  const int n = gid & (NN - 1);
  const int b = gid >> 10;
  const float sr = s1[b * TWO_N + 2 * n], si = s1[b * TWO_N + 2 * n + 1];
  const float2 c = C1last[n];
  s1c[b * TWO_N + 2 * n]     = c.x * sr - c.y * si;
  s1c[b * TWO_N + 2 * n + 1] = c.x * si + c.y * sr;
}

// ---------------- tail GEMM: one wave per output, A [M,K] f32, BT [N,K] f32 ----------------
__global__ __launch_bounds__(256) void k_tail(const float* __restrict__ A,
                                              const float* __restrict__ BT,
                                              float* __restrict__ C, int M, int N, int K) {
  const int wave = threadIdx.x >> 6;
  const int lane = threadIdx.x & 63;
  const int o = blockIdx.x * 4 + wave;     // output index
  if (o >= M * N) return;
  const int row = o / N;
  const int col = o - row * N;
  const float4* __restrict__ a4 = (const float4*)(A + (size_t)row * K);
  const float4* __restrict__ b4 = (const float4*)(BT + (size_t)col * K);
  float acc = 0.f;
  const int nit = K >> 8;                  // K / (64 lanes * 4)
  for (int it = 0; it < nit; ++it) {
    const float4 av = a4[it * 64 + lane];
    const float4 bv = b4[it * 64 + lane];
    acc = fmaf(av.x, bv.x, acc);
    acc = fmaf(av.y, bv.y, acc);
    acc = fmaf(av.z, bv.z, acc);
    acc = fmaf(av.w, bv.w, acc);
  }
#pragma unroll
  for (int s = 32; s >= 1; s >>= 1) acc += __shfl_xor(acc, s);
  if (lane == 0) C[o] = acc;
}

// ---------------- weight packing ----------------
__global__ __launch_bounds__(256) void k_prep_in(const float* __restrict__ r, const float* __restrict__ im,
                                                 _Float16* __restrict__ dst) {
  const int gid = blockIdx.x * 256 + threadIdx.x;  // k*NN + n
  const int n = gid & (NN - 1);
  const int k = gid >> 10;
  const float rv = r[(size_t)k * NN + n], iv = im[(size_t)k * NN + n];
  const size_t base = (size_t)(2 * n) * TWO_K + 2 * k;
  dst[base] = (_Float16)rv;              dst[base + 1] = (_Float16)(-iv);
  dst[base + TWO_K] = (_Float16)iv;      dst[base + TWO_K + 1] = (_Float16)rv;
}
__global__ __launch_bounds__(256) void k_prep_out(const float* __restrict__ r, const float* __restrict__ im,
                                                  _Float16* __restrict__ dst) {
  const int gid = blockIdx.x * 256 + threadIdx.x;  // n*DD + d
  const int d = gid & (DD - 1);
  const int n = gid >> 8;
  const float rv = r[(size_t)n * DD + d], iv = im[(size_t)n * DD + d];
  const size_t base = (size_t)(2 * d) * TWO_N + 2 * n;
  dst[base] = (_Float16)rv;              dst[base + 1] = (_Float16)(-iv);
  dst[base + TWO_N] = (_Float16)iv;      dst[base + TWO_N + 1] = (_Float16)rv;
}
__global__ __launch_bounds__(256) void k_prep_wout1T(const float* __restrict__ r, const float* __restrict__ im,
                                                     float* __restrict__ dstT) {
  const int gid = blockIdx.x * 256 + threadIdx.x;  // d*NN + n
  const int n = gid & (NN - 1);
  const int d = gid >> 10;
  const float rv = r[(size_t)n * DD + d], iv = im[(size_t)n * DD + d];
  const size_t b0 = (size_t)(2 * d) * TWO_N + 2 * n;
  const size_t b1 = (size_t)(2 * d + 1) * TWO_N + 2 * n;
  dstT[b0] = rv;     dstT[b0 + 1] = -iv;
  dstT[b1] = iv;     dstT[b1 + 1] = rv;
}
__global__ __launch_bounds__(256) void k_prep_finT(const float* __restrict__ pr, const float* __restrict__ pi_,
                                                   float* __restrict__ dstT) {
  const int gid = blockIdx.x * 256 + threadIdx.x;  // s*DD + d
  const int d = gid & (DD - 1);
  const int s = gid >> 8;
  const float a = pr[(size_t)d * 256 + s], b = pi_[(size_t)d * 256 + s];
  dstT[(size_t)s * TWO_K + 2 * d] = a + b;
  dstT[(size_t)s * TWO_K + 2 * d + 1] = a - b;
}

extern "C" void kernel_launch(void* const* d_in, const int* in_sizes, int n_in,
                              void* d_out, int out_size, void* d_ws, size_t ws_size,
                              hipStream_t stream) {
  const int* ids      = (const int*)d_in[0];
  const float* emb    = (const float*)d_in[1];
  const float* win_r  = (const float*)d_in[2];
  const float* win_i  = (const float*)d_in[3];
  const float* wout_r = (const float*)d_in[4];
  const float* wout_i = (const float*)d_in[5];
  const float* omega  = (const float*)d_in[6];
  const float* outp_r = (const float*)d_in[7];
  const float* outp_i = (const float*)d_in[8];

  char* ws = (char*)d_ws;
  size_t off = 0;
  auto alloc = [&](size_t bytes) { void* p = ws + off; off += (bytes + 255) & ~(size_t)255; return p; };

  float2* C0     = (float2*)alloc((size_t)S_LEN * NN * 8);
  float2* D0     = (float2*)alloc((size_t)S_LEN * NN * 8);
  float2* D1     = (float2*)alloc((size_t)S_LEN * NN * 8);
  float2* C1last = (float2*)alloc((size_t)NN * 8);
  float2* ZS     = (float2*)alloc((size_t)BB * NN * 8);
  float* hstate  = (float*)alloc((size_t)BB * DD * 2 * 4);
  float* s1      = (float*)alloc((size_t)BB * TWO_N * 4);
  float* s1c     = (float*)alloc((size_t)BB * TWO_N * 4);
  float* xt      = (float*)alloc((size_t)BB * TWO_K * 4);
  _Float16* BTin0  = (_Float16*)alloc((size_t)TWO_N * TWO_K * 2);
  _Float16* BTout0 = (_Float16*)alloc((size_t)TWO_K * TWO_N * 2);
  _Float16* BTin1  = (_Float16*)alloc((size_t)TWO_N * TWO_K * 2);
  float* Wout1T = (float*)alloc((size_t)TWO_K * TWO_N * 4);
  float* WfinT  = (float*)alloc((size_t)256 * TWO_K * 4);
  const size_t fixed = off;

  // per-chunk buffers: X0 [CH*BB, TWO_K] f16, VB [CH*BB, TWO_N] f16; Yc aliases X0
  int CH = 1024;
  while (CH > 32) {
    size_t need = fixed + (size_t)CH * BB * 2 * (TWO_K + TWO_N) + 2 * 256;
    if (need <= ws_size) break;
    CH >>= 1;
  }
  _Float16* X0 = (_Float16*)alloc((size_t)CH * BB * TWO_K * 2);
  _Float16* VB = (_Float16*)alloc((size_t)CH * BB * TWO_N * 2);
  _Float16* Yc = X0;

  k_rot<<<2 * NN, 256, 0, stream>>>(omega, C0, D0, D1, C1last);
  k_prep_in<<<DD * NN / 256, 256, 0, stream>>>(win_r, win_i, BTin0);
  k_prep_in<<<DD * NN / 256, 256, 0, stream>>>(win_r + (size_t)DD * NN, win_i + (size_t)DD * NN, BTin1);
  k_prep_out<<<NN * DD / 256, 256, 0, stream>>>(wout_r, wout_i, BTout0);
  k_prep_wout1T<<<NN * DD / 256, 256, 0, stream>>>(wout_r + (size_t)NN * DD, wout_i + (size_t)NN * DD, Wout1T);
  k_prep_finT<<<DD * 256 / 256, 256, 0, stream>>>(outp_r, outp_i, WfinT);

  const int nchunks = S_LEN / CH;
  for (int c = 0; c < nchunks; ++c) {
    const int t0 = c * CH;
    const int M = CH * BB;
    k_h<<<BB, 256, 0, stream>>>(ids, emb, hstate, X0, t0, CH);
    dim3 g1(TWO_N / 128, M / 128);
    k_gemm<<<g1, 256, 0, stream>>>(X0, BTin0, VB, M, TWO_N, TWO_K, D0 + (size_t)t0 * NN);
    k_scan<<<BB * (NN / 2) / 256, 256, 0, stream>>>(VB, C0 + (size_t)t0 * NN, ZS, CH, c == 0);
    dim3 g2(TWO_K / 128, M / 128);
    k_gemm<<<g2, 256, 0, stream>>>(VB, BTout0, Yc, M, TWO_K, TWO_N, nullptr);
    k_gemm<<<g1, 256, 0, stream>>>(Yc, BTin1, VB, M, TWO_N, TWO_K, D1 + (size_t)t0 * NN);
    k_reduce<<<BB * (TWO_N / 4) / 256, 256, 0, stream>>>(VB, s1, CH, c == 0);
  }

  k_s1c<<<BB * NN / 256, 256, 0, stream>>>(s1, C1last, s1c);
  // xt[128, 512] = s1c[128, 2048] @ Wout1 (via Wout1T [512, 2048])
  k_tail<<<BB * TWO_K / 4, 256, 0, stream>>>(s1c, Wout1T, xt, BB, TWO_K, TWO_N);
  // out[128, 256] = xt[128, 512] @ Wfin (via WfinT [256, 512])
  k_tail<<<BB * 256 / 4, 256, 0, stream>>>(xt, WfinT, (float*)d_out, BB, 256, TWO_K);
}

// Round 7
// 1957.328 us; speedup vs baseline: 1.9715x; 1.0340x over previous
//
#include <hip/hip_runtime.h>

#define S_LEN 1024
#define BB 128
#define DD 256
#define NN 1024
#define TWO_K 512   // 2*DD
#define TWO_N 2048  // 2*NN

typedef _Float16 half8 __attribute__((ext_vector_type(8)));
typedef _Float16 half4 __attribute__((ext_vector_type(4)));
typedef float f32x4 __attribute__((ext_vector_type(4)));

__device__ __forceinline__ float wrap2pi(float x) {
  float r = fmodf(x, 6.283185307179586f);
  if (r < 0.f) r += 6.283185307179586f;
  return r;
}
__device__ __forceinline__ int lut_index(float th) {
  float w = wrap2pi(th);
  return ((int)floorf(w * 651.8986469044033f)) & 4095;
}

// ---------------- h recurrence (pointwise over b,d) -> X0 [CH*BB, 2*DD] f16 interleaved ----------------
// LDS-staged: emb rows for the next 8-t stage are prefetched via global_load_lds (width 16)
// into a double-buffered ebuf while the current stage's serial h-chain computes. tphi is a
// per-t LDS table (lane-invariant). Arithmetic/order identical to prior rounds -> bit-identical X0.
__global__ __launch_bounds__(256) void k_h(const int* __restrict__ ids,
                                           const float* __restrict__ emb,
                                           float* __restrict__ hstate,
                                           _Float16* __restrict__ X0,
                                           int t0, int CH) {
  __shared__ __align__(16) float2 lut[4096];          // 32 KB
  __shared__ __align__(16) float ebuf[2][8][2][256];  // 32 KB: buf, j, (w|bv), d
  __shared__ float tphi_s[1024];                      // 4 KB
  const int tid = threadIdx.x;
  const int lane = tid & 63;
  const int wv = tid >> 6;
  for (int i = tid; i < 4096; i += 256) {
    float ang = 0.0015339807878856412f * (float)i;
    lut[i] = make_float2(sinf(ang), cosf(ang));
  }
  for (int i = tid; i < CH; i += 256)
    tphi_s[i] = wrap2pi((float)(t0 + i) * 1.618033988749895f);

  const int b = blockIdx.x;
  const int d = tid;
  const int* __restrict__ idrow = ids + b * S_LEN + t0;
  const int NST = CH >> 3;

  // prefetch stage 0 into buf 0: wave wv stages ids j = 2*wv, 2*wv+1 (2 segs each)
#pragma unroll
  for (int q = 0; q < 2; ++q) {
    const int j = wv * 2 + q;
    const int id = idrow[j];
    const float* src = emb + (size_t)id * 512 + lane * 4;
    __builtin_amdgcn_global_load_lds((const __attribute__((address_space(1))) void*)src,
                                     (__attribute__((address_space(3))) void*)(&ebuf[0][j][0][0]), 16, 0, 0);
    __builtin_amdgcn_global_load_lds((const __attribute__((address_space(1))) void*)(src + 256),
                                     (__attribute__((address_space(3))) void*)(&ebuf[0][j][1][0]), 16, 0, 0);
  }

  float hr, hi;
  if (t0 == 0) { hr = 0.f; hi = 0.f; }
  else { float2 h = ((const float2*)hstate)[b * DD + d]; hr = h.x; hi = h.y; }

  int buf = 0;
  __syncthreads();  // drains vmcnt (stage-0 prefetch) + lut/tphi writes

  for (int st = 0; st < NST; ++st) {
    if (st + 1 < NST) {
#pragma unroll
      for (int q = 0; q < 2; ++q) {
        const int j = wv * 2 + q;
        const int id = idrow[(st + 1) * 8 + j];
        const float* src = emb + (size_t)id * 512 + lane * 4;
        __builtin_amdgcn_global_load_lds((const __attribute__((address_space(1))) void*)src,
                                         (__attribute__((address_space(3))) void*)(&ebuf[buf ^ 1][j][0][0]), 16, 0, 0);
        __builtin_amdgcn_global_load_lds((const __attribute__((address_space(1))) void*)(src + 256),
                                         (__attribute__((address_space(3))) void*)(&ebuf[buf ^ 1][j][1][0]), 16, 0, 0);
      }
    }
#pragma unroll
    for (int j = 0; j < 8; ++j) {
      const int tt = st * 8 + j;
      const float w  = ebuf[buf][j][0][d];
      const float bv = ebuf[buf][j][1][d];
      const float wl = 1.f + fabsf(w);
      const float tphi = tphi_s[tt];
      const float thr = hr / wl + bv + tphi;
      const float thi = hi / wl + bv + tphi;
      const float2 a = lut[lut_index(thr)];
      const float2 c = lut[lut_index(thi)];
      hr = a.y * c.y - a.x * c.x;
      hi = a.y * c.x + a.x * c.y;
      union { unsigned int u; _Float16 h2[2]; } pk;
      pk.h2[0] = (_Float16)hr; pk.h2[1] = (_Float16)hi;
      *(((unsigned int*)(X0 + (size_t)(tt * BB + b) * TWO_K)) + d) = pk.u;
    }
    __syncthreads();  // prefetch landed; all waves done with ebuf[buf]
    buf ^= 1;
  }
  ((float2*)hstate)[b * DD + d] = make_float2(hr, hi);
}

// ---------------- rotation prefix via parallel integer scan ----------------
__global__ __launch_bounds__(256) void k_rot(const float* __restrict__ omega,
                                             float2* __restrict__ C0, float2* __restrict__ D0,
                                             float2* __restrict__ D1, float2* __restrict__ C1last) {
  const int blk = blockIdx.x;               // 0..2047
  const int l = blk >> 10, n = blk & (NN - 1);
  const int tid = threadIdx.x;
  const int lane = tid & 63;
  const int wid = tid >> 6;
  const float om = omega[l * NN + n];

  int pre[4];
  int own = 0;
  const int tb = tid * 4;
#pragma unroll
  for (int j = 0; j < 4; ++j) {
    own += lut_index(om + (float)(tb + j) * 1.618033988749895f);
    pre[j] = own;
  }
  int v = own;
#pragma unroll
  for (int off = 1; off < 64; off <<= 1) {
    int u = __shfl_up(v, off);
    if (lane >= off) v += u;
  }
  __shared__ int wsum[4];
  if (lane == 63) wsum[wid] = v;
  __syncthreads();
  int woff = 0;
#pragma unroll
  for (int w = 0; w < 4; ++w) woff += (w < wid) ? wsum[w] : 0;
  const int excl = woff + v - own;

#pragma unroll
  for (int j = 0; j < 4; ++j) {
    const int t = tb + j;
    const int idx = (excl + pre[j]) & 4095;
    const float s = sinf(0.0015339807878856412f * (float)idx);
    const float c = cosf(0.0015339807878856412f * (float)idx);
    if (l == 0) {
      C0[t * NN + n] = make_float2(c, s);
      D0[t * NN + n] = make_float2(c, -s);
    } else {
      D1[t * NN + n] = make_float2(c, -s);
      if (t == S_LEN - 1) C1last[n] = make_float2(c, s);
    }
  }
}

// ---------------- f16 MFMA GEMM: C = A @ BT^T, optional complex rotation epilogue ----------------
__global__ __launch_bounds__(256, 2) void k_gemm(const _Float16* __restrict__ A,
                                                 const _Float16* __restrict__ BT,
                                                 _Float16* __restrict__ C,
                                                 int M, int N, int K,
                                                 const float2* __restrict__ rot) {
  __shared__ __align__(16) _Float16 As[128 * 64];
  __shared__ __align__(16) _Float16 Bs[128 * 64];
  const int tid = threadIdx.x;
  const int lane = tid & 63;
  const int wave = tid >> 6;
  const int wm = wave >> 1;
  const int wn = wave & 1;
  const int m0 = blockIdx.y * 128;
  const int n0 = blockIdx.x * 128;

  const int srow = lane >> 3;               // row within 8-row chunk
  const int schunk = (lane & 7) ^ srow;     // XOR-swizzled source 16B-chunk

  f32x4 acc[4][4] = {};

  for (int kt = 0; kt < K; kt += 64) {
#pragma unroll
    for (int j = 0; j < 4; ++j) {
      const int c = wave * 4 + j;           // chunk 0..15, covers rows c*8..c*8+7
      const int row = c * 8 + srow;
      const _Float16* srcA = A + (size_t)(m0 + row) * K + kt + schunk * 8;
      __builtin_amdgcn_global_load_lds((const __attribute__((address_space(1))) void*)srcA,
                                       (__attribute__((address_space(3))) void*)(As + c * 512), 16, 0, 0);
      const _Float16* srcB = BT + (size_t)(n0 + row) * K + kt + schunk * 8;
      __builtin_amdgcn_global_load_lds((const __attribute__((address_space(1))) void*)srcB,
                                       (__attribute__((address_space(3))) void*)(Bs + c * 512), 16, 0, 0);
    }
    __syncthreads();
#pragma unroll
    for (int ks = 0; ks < 2; ++ks) {
      half8 af[4], bf[4];
#pragma unroll
      for (int mr = 0; mr < 4; ++mr) {
        const int ar = wm * 64 + mr * 16 + (lane & 15);
        const int p = ((ks * 4) + (lane >> 4)) ^ (ar & 7);
        af[mr] = *(const half8*)(As + ar * 64 + p * 8);
      }
#pragma unroll
      for (int nr = 0; nr < 4; ++nr) {
        const int br = wn * 64 + nr * 16 + (lane & 15);
        const int p = ((ks * 4) + (lane >> 4)) ^ (br & 7);
        bf[nr] = *(const half8*)(Bs + br * 64 + p * 8);
      }
#pragma unroll
      for (int mr = 0; mr < 4; ++mr)
#pragma unroll
        for (int nr = 0; nr < 4; ++nr)
          acc[mr][nr] = __builtin_amdgcn_mfma_f32_16x16x32_f16(af[mr], bf[nr], acc[mr][nr], 0, 0, 0);
    }
    __syncthreads();
  }

  const int halfN = N >> 1;
  const int t = blockIdx.y;
#pragma unroll
  for (int mr = 0; mr < 4; ++mr)
#pragma unroll
    for (int nr = 0; nr < 4; ++nr) {
      const int col = n0 + wn * 64 + nr * 16 + (lane & 15);
      const int rbase = m0 + wm * 64 + mr * 16 + ((lane >> 4) << 2);
      float2 dr = make_float2(1.f, 0.f);
      if (rot) dr = rot[(size_t)t * halfN + (col >> 1)];
#pragma unroll
      for (int j = 0; j < 4; ++j) {
        float v = acc[mr][nr][j];
        if (rot) {
          const float pv = __shfl_xor(v, 1);
          v = (lane & 1) ? (dr.x * v + dr.y * pv) : (dr.x * v - dr.y * pv);
        }
        C[(size_t)(rbase + j) * N + col] = (_Float16)v;
      }
    }
}

// ---------------- prefix-sum over t (in place), then multiply by C0[t] ----------------
// 2 complex/thread, unroll-8 with register double-buffered prefetch (latency cover).
#define SUF 8
__global__ __launch_bounds__(256) void k_scan(_Float16* __restrict__ V,          // [CH*BB, TWO_N]
                                              const float2* __restrict__ C0c,    // [CH, NN]
                                              float2* __restrict__ ZS, int CH, int first) {
  const int gid = blockIdx.x * 256 + threadIdx.x;  // b*(NN/2) + npair
  const int npair = gid & (NN / 2 - 1);
  const int b = gid >> 9;
  const int n = npair * 2;
  float zr0, zi0, zr1, zi1;
  if (first) { zr0 = zi0 = zr1 = zi1 = 0.f; }
  else {
    float4 z = *(const float4*)(ZS + (size_t)b * NN + n);
    zr0 = z.x; zi0 = z.y; zr1 = z.z; zi1 = z.w;
  }
  uint2 vb[SUF], vn[SUF];
  float4 cb[SUF], cn[SUF];
#pragma unroll
  for (int j = 0; j < SUF; ++j) {
    vb[j] = *(const uint2*)(((const unsigned int*)(V + (size_t)(j * BB + b) * TWO_N)) + n);
    cb[j] = *(const float4*)(C0c + (size_t)j * NN + n);
  }
  for (int st = 0; st < CH; st += SUF) {
    const bool more = (st + SUF) < CH;
    if (more) {
#pragma unroll
      for (int j = 0; j < SUF; ++j) {
        vn[j] = *(const uint2*)(((const unsigned int*)(V + (size_t)((st + SUF + j) * BB + b) * TWO_N)) + n);
        cn[j] = *(const float4*)(C0c + (size_t)(st + SUF + j) * NN + n);
      }
    }
#pragma unroll
    for (int j = 0; j < SUF; ++j) {
      union { unsigned int u; _Float16 h2[2]; } a, c;
      a.u = vb[j].x; c.u = vb[j].y;
      zr0 += (float)a.h2[0]; zi0 += (float)a.h2[1];
      zr1 += (float)c.h2[0]; zi1 += (float)c.h2[1];
      const float4 cc = cb[j];
      a.h2[0] = (_Float16)(cc.x * zr0 - cc.y * zi0);
      a.h2[1] = (_Float16)(cc.x * zi0 + cc.y * zr0);
      c.h2[0] = (_Float16)(cc.z * zr1 - cc.w * zi1);
      c.h2[1] = (_Float16)(cc.z * zi1 + cc.w * zr1);
      *(uint2*)(((unsigned int*)(V + (size_t)((st + j) * BB + b) * TWO_N)) + n) = make_uint2(a.u, c.u);
    }
#pragma unroll
    for (int j = 0; j < SUF; ++j) { vb[j] = vn[j]; cb[j] = cn[j]; }
  }
  *(float4*)(ZS + (size_t)b * NN + n) = make_float4(zr0, zi0, zr1, zi1);
}

// ---------------- reduce over t: s1[b, np4] += sum_t U[t,b,np4] ----------------
// 4 halves/thread (65536 threads), unroll-8 register double-buffered prefetch.
__global__ __launch_bounds__(256) void k_reduce(const _Float16* __restrict__ U,  // [CH*BB, TWO_N]
                                                float* __restrict__ s1, int CH, int first) {
  const int gid = blockIdx.x * 256 + threadIdx.x;  // b*(TWO_N/4) + g
  const int g = gid & (TWO_N / 4 - 1);
  const int b = gid >> 9;
  const int np = g * 4;
  f32x4 acc;
  if (first) {
#pragma unroll
    for (int j = 0; j < 4; ++j) acc[j] = 0.f;
  } else {
    acc = *(const f32x4*)(s1 + (size_t)b * TWO_N + np);
  }
  half4 vb[SUF], vn[SUF];
#pragma unroll
  for (int j = 0; j < SUF; ++j)
    vb[j] = *(const half4*)(U + (size_t)(j * BB + b) * TWO_N + np);
  for (int st = 0; st < CH; st += SUF) {
    const bool more = (st + SUF) < CH;
    if (more) {
#pragma unroll
      for (int j = 0; j < SUF; ++j)
        vn[j] = *(const half4*)(U + (size_t)((st + SUF + j) * BB + b) * TWO_N + np);
    }
#pragma unroll
    for (int j = 0; j < SUF; ++j) {
#pragma unroll
      for (int q = 0; q < 4; ++q) acc[q] += (float)vb[j][q];
    }
#pragma unroll
    for (int j = 0; j < SUF; ++j) vb[j] = vn[j];
  }
  *(f32x4*)(s1 + (size_t)b * TWO_N + np) = acc;
}

// ---------------- s1c = C1last (*) s1 ----------------
__global__ __launch_bounds__(256) void k_s1c(const float* __restrict__ s1,
                                             const float2* __restrict__ C1last,
                                             float* __restrict__ s1c) {
  const int gid = blockIdx.x * 256 + threadIdx.x;  // b*NN + n
  const int n = gid & (NN - 1);
  const int b = gid >> 10;
  const float sr = s1[b * TWO_N + 2 * n], si = s1[b * TWO_N + 2 * n + 1];
  const float2 c = C1last[n];
  s1c[b * TWO_N + 2 * n]     = c.x * sr - c.y * si;
  s1c[b * TWO_N + 2 * n + 1] = c.x * si + c.y * sr;
}

// ---------------- tail GEMM: one wave per output, A [M,K] f32, BT [N,K] f32 ----------------
__global__ __launch_bounds__(256) void k_tail(const float* __restrict__ A,
                                              const float* __restrict__ BT,
                                              float* __restrict__ C, int M, int N, int K) {
  const int wave = threadIdx.x >> 6;
  const int lane = threadIdx.x & 63;
  const int o = blockIdx.x * 4 + wave;     // output index
  if (o >= M * N) return;
  const int row = o / N;
  const int col = o - row * N;
  const float4* __restrict__ a4 = (const float4*)(A + (size_t)row * K);
  const float4* __restrict__ b4 = (const float4*)(BT + (size_t)col * K);
  float acc = 0.f;
  const int nit = K >> 8;                  // K / (64 lanes * 4)
  for (int it = 0; it < nit; ++it) {
    const float4 av = a4[it * 64 + lane];
    const float4 bv = b4[it * 64 + lane];
    acc = fmaf(av.x, bv.x, acc);
    acc = fmaf(av.y, bv.y, acc);
    acc = fmaf(av.z, bv.z, acc);
    acc = fmaf(av.w, bv.w, acc);
  }
#pragma unroll
  for (int s = 32; s >= 1; s >>= 1) acc += __shfl_xor(acc, s);
  if (lane == 0) C[o] = acc;
}

// ---------------- weight packing ----------------
__global__ __launch_bounds__(256) void k_prep_in(const float* __restrict__ r, const float* __restrict__ im,
                                                 _Float16* __restrict__ dst) {
  const int gid = blockIdx.x * 256 + threadIdx.x;  // k*NN + n
  const int n = gid & (NN - 1);
  const int k = gid >> 10;
  const float rv = r[(size_t)k * NN + n], iv = im[(size_t)k * NN + n];
  const size_t base = (size_t)(2 * n) * TWO_K + 2 * k;
  dst[base] = (_Float16)rv;              dst[base + 1] = (_Float16)(-iv);
  dst[base + TWO_K] = (_Float16)iv;      dst[base + TWO_K + 1] = (_Float16)rv;
}
__global__ __launch_bounds__(256) void k_prep_out(const float* __restrict__ r, const float* __restrict__ im,
                                                  _Float16* __restrict__ dst) {
  const int gid = blockIdx.x * 256 + threadIdx.x;  // n*DD + d
  const int d = gid & (DD - 1);
  const int n = gid >> 8;
  const float rv = r[(size_t)n * DD + d], iv = im[(size_t)n * DD + d];
  const size_t base = (size_t)(2 * d) * TWO_N + 2 * n;
  dst[base] = (_Float16)rv;              dst[base + 1] = (_Float16)(-iv);
  dst[base + TWO_N] = (_Float16)iv;      dst[base + TWO_N + 1] = (_Float16)rv;
}
__global__ __launch_bounds__(256) void k_prep_wout1T(const float* __restrict__ r, const float* __restrict__ im,
                                                     float* __restrict__ dstT) {
  const int gid = blockIdx.x * 256 + threadIdx.x;  // d*NN + n
  const int n = gid & (NN - 1);
  const int d = gid >> 10;
  const float rv = r[(size_t)n * DD + d], iv = im[(size_t)n * DD + d];
  const size_t b0 = (size_t)(2 * d) * TWO_N + 2 * n;
  const size_t b1 = (size_t)(2 * d + 1) * TWO_N + 2 * n;
  dstT[b0] = rv;     dstT[b0 + 1] = -iv;
  dstT[b1] = iv;     dstT[b1 + 1] = rv;
}
__global__ __launch_bounds__(256) void k_prep_finT(const float* __restrict__ pr, const float* __restrict__ pi_,
                                                   float* __restrict__ dstT) {
  const int gid = blockIdx.x * 256 + threadIdx.x;  // s*DD + d
  const int d = gid & (DD - 1);
  const int s = gid >> 8;
  const float a = pr[(size_t)d * 256 + s], b = pi_[(size_t)d * 256 + s];
  dstT[(size_t)s * TWO_K + 2 * d] = a + b;
  dstT[(size_t)s * TWO_K + 2 * d + 1] = a - b;
}

extern "C" void kernel_launch(void* const* d_in, const int* in_sizes, int n_in,
                              void* d_out, int out_size, void* d_ws, size_t ws_size,
                              hipStream_t stream) {
  const int* ids      = (const int*)d_in[0];
  const float* emb    = (const float*)d_in[1];
  const float* win_r  = (const float*)d_in[2];
  const float* win_i  = (const float*)d_in[3];
  const float* wout_r = (const float*)d_in[4];
  const float* wout_i = (const float*)d_in[5];
  const float* omega  = (const float*)d_in[6];
  const float* outp_r = (const float*)d_in[7];
  const float* outp_i = (const float*)d_in[8];

  char* ws = (char*)d_ws;
  size_t off = 0;
  auto alloc = [&](size_t bytes) { void* p = ws + off; off += (bytes + 255) & ~(size_t)255; return p; };

  float2* C0     = (float2*)alloc((size_t)S_LEN * NN * 8);
  float2* D0     = (float2*)alloc((size_t)S_LEN * NN * 8);
  float2* D1     = (float2*)alloc((size_t)S_LEN * NN * 8);
  float2* C1last = (float2*)alloc((size_t)NN * 8);
  float2* ZS     = (float2*)alloc((size_t)BB * NN * 8);
  float* hstate  = (float*)alloc((size_t)BB * DD * 2 * 4);
  float* s1      = (float*)alloc((size_t)BB * TWO_N * 4);
  float* s1c     = (float*)alloc((size_t)BB * TWO_N * 4);
  float* xt      = (float*)alloc((size_t)BB * TWO_K * 4);
  _Float16* BTin0  = (_Float16*)alloc((size_t)TWO_N * TWO_K * 2);
  _Float16* BTout0 = (_Float16*)alloc((size_t)TWO_K * TWO_N * 2);
  _Float16* BTin1  = (_Float16*)alloc((size_t)TWO_N * TWO_K * 2);
  float* Wout1T = (float*)alloc((size_t)TWO_K * TWO_N * 4);
  float* WfinT  = (float*)alloc((size_t)256 * TWO_K * 4);
  const size_t fixed = off;

  // per-chunk buffers: X0 [CH*BB, TWO_K] f16, VB [CH*BB, TWO_N] f16; Yc aliases X0
  int CH = 1024;
  while (CH > 32) {
    size_t need = fixed + (size_t)CH * BB * 2 * (TWO_K + TWO_N) + 2 * 256;
    if (need <= ws_size) break;
    CH >>= 1;
  }
  _Float16* X0 = (_Float16*)alloc((size_t)CH * BB * TWO_K * 2);
  _Float16* VB = (_Float16*)alloc((size_t)CH * BB * TWO_N * 2);
  _Float16* Yc = X0;

  k_rot<<<2 * NN, 256, 0, stream>>>(omega, C0, D0, D1, C1last);
  k_prep_in<<<DD * NN / 256, 256, 0, stream>>>(win_r, win_i, BTin0);
  k_prep_in<<<DD * NN / 256, 256, 0, stream>>>(win_r + (size_t)DD * NN, win_i + (size_t)DD * NN, BTin1);
  k_prep_out<<<NN * DD / 256, 256, 0, stream>>>(wout_r, wout_i, BTout0);
  k_prep_wout1T<<<NN * DD / 256, 256, 0, stream>>>(wout_r + (size_t)NN * DD, wout_i + (size_t)NN * DD, Wout1T);
  k_prep_finT<<<DD * 256 / 256, 256, 0, stream>>>(outp_r, outp_i, WfinT);

  const int nchunks = S_LEN / CH;
  for (int c = 0; c < nchunks; ++c) {
    const int t0 = c * CH;
    const int M = CH * BB;
    k_h<<<BB, 256, 0, stream>>>(ids, emb, hstate, X0, t0, CH);
    dim3 g1(TWO_N / 128, M / 128);
    k_gemm<<<g1, 256, 0, stream>>>(X0, BTin0, VB, M, TWO_N, TWO_K, D0 + (size_t)t0 * NN);
    k_scan<<<BB * (NN / 2) / 256, 256, 0, stream>>>(VB, C0 + (size_t)t0 * NN, ZS, CH, c == 0);
    dim3 g2(TWO_K / 128, M / 128);
    k_gemm<<<g2, 256, 0, stream>>>(VB, BTout0, Yc, M, TWO_K, TWO_N, nullptr);
    k_gemm<<<g1, 256, 0, stream>>>(Yc, BTin1, VB, M, TWO_N, TWO_K, D1 + (size_t)t0 * NN);
    k_reduce<<<BB * (TWO_N / 4) / 256, 256, 0, stream>>>(VB, s1, CH, c == 0);
  }

  k_s1c<<<BB * NN / 256, 256, 0, stream>>>(s1, C1last, s1c);
  // xt[128, 512] = s1c[128, 2048] @ Wout1 (via Wout1T [512, 2048])
  k_tail<<<BB * TWO_K / 4, 256, 0, stream>>>(s1c, Wout1T, xt, BB, TWO_K, TWO_N);
  // out[128, 256] = xt[128, 512] @ Wfin (via WfinT [256, 512])
  k_tail<<<BB * 256 / 4, 256, 0, stream>>>(xt, WfinT, (float*)d_out, BB, 256, TWO_K);
}

// Round 8
// 1635.841 us; speedup vs baseline: 2.3589x; 1.1965x over previous
//
#include <hip/hip_runtime.h>

#define S_LEN 1024
#define BB 128
#define DD 256
#define NN 1024
#define TWO_K 512   // 2*DD
#define TWO_N 2048  // 2*NN

typedef _Float16 half8 __attribute__((ext_vector_type(8)));
typedef _Float16 half4 __attribute__((ext_vector_type(4)));
typedef float f32x4 __attribute__((ext_vector_type(4)));

__device__ __forceinline__ float wrap2pi(float x) {
  float r = fmodf(x, 6.283185307179586f);
  if (r < 0.f) r += 6.283185307179586f;
  return r;
}
__device__ __forceinline__ int lut_index(float th) {
  float w = wrap2pi(th);
  return ((int)floorf(w * 651.8986469044033f)) & 4095;
}
// quantized phase as a fraction of a revolution: floor(th*4096/2pi) mod 4096, /4096.
// 2^-12 mul and fract are exact -> exactly (idx&4095)/4096 for idx=floor(th*s).
__device__ __forceinline__ float q12(float th) {
  const float y = floorf(th * 651.8986469044033f) * 0.000244140625f;
  return y - floorf(y);
}

// ---------------- h recurrence (pointwise over b,d) -> X0 [CH*BB, 2*DD] f16 interleaved ----------------
// LDS-staged emb (double-buffered, global_load_lds w16). Per-iter chain reduced to
// fma -> mul -> floor -> fract -> v_sin/v_cos -> cmul; rwl=1/(1+|w|) and bvt=bv+tphi
// are h-independent and precomputed off-chain each stage.
__global__ __launch_bounds__(256) void k_h(const int* __restrict__ ids,
                                           const float* __restrict__ emb,
                                           float* __restrict__ hstate,
                                           _Float16* __restrict__ X0,
                                           int t0, int CH) {
  __shared__ __align__(16) float ebuf[2][8][2][256];  // 32 KB: buf, j, (w|bv), d
  __shared__ float tphi_s[1024];                      // 4 KB
  const int tid = threadIdx.x;
  const int lane = tid & 63;
  const int wv = tid >> 6;
  for (int i = tid; i < CH; i += 256)
    tphi_s[i] = wrap2pi((float)(t0 + i) * 1.618033988749895f);

  const int b = blockIdx.x;
  const int d = tid;
  const int* __restrict__ idrow = ids + b * S_LEN + t0;
  const int NST = CH >> 3;

#pragma unroll
  for (int q = 0; q < 2; ++q) {
    const int j = wv * 2 + q;
    const int id = idrow[j];
    const float* src = emb + (size_t)id * 512 + lane * 4;
    __builtin_amdgcn_global_load_lds((const __attribute__((address_space(1))) void*)src,
                                     (__attribute__((address_space(3))) void*)(&ebuf[0][j][0][0]), 16, 0, 0);
    __builtin_amdgcn_global_load_lds((const __attribute__((address_space(1))) void*)(src + 256),
                                     (__attribute__((address_space(3))) void*)(&ebuf[0][j][1][0]), 16, 0, 0);
  }

  float hr, hi;
  if (t0 == 0) { hr = 0.f; hi = 0.f; }
  else { float2 h = ((const float2*)hstate)[b * DD + d]; hr = h.x; hi = h.y; }

  int buf = 0;
  __syncthreads();  // drains vmcnt (stage-0 prefetch) + tphi writes

  for (int st = 0; st < NST; ++st) {
    if (st + 1 < NST) {
#pragma unroll
      for (int q = 0; q < 2; ++q) {
        const int j = wv * 2 + q;
        const int id = idrow[(st + 1) * 8 + j];
        const float* src = emb + (size_t)id * 512 + lane * 4;
        __builtin_amdgcn_global_load_lds((const __attribute__((address_space(1))) void*)src,
                                         (__attribute__((address_space(3))) void*)(&ebuf[buf ^ 1][j][0][0]), 16, 0, 0);
        __builtin_amdgcn_global_load_lds((const __attribute__((address_space(1))) void*)(src + 256),
                                         (__attribute__((address_space(3))) void*)(&ebuf[buf ^ 1][j][1][0]), 16, 0, 0);
      }
    }
    // off-chain per-stage precompute (independent of h)
    float rwl[8], bvt[8];
#pragma unroll
    for (int j = 0; j < 8; ++j) {
      const float w  = ebuf[buf][j][0][d];
      const float bv = ebuf[buf][j][1][d];
      rwl[j] = 1.0f / (1.f + fabsf(w));
      bvt[j] = bv + tphi_s[st * 8 + j];
    }
    // serial h chain (short)
#pragma unroll
    for (int j = 0; j < 8; ++j) {
      const int tt = st * 8 + j;
      const float thr = fmaf(hr, rwl[j], bvt[j]);
      const float thi = fmaf(hi, rwl[j], bvt[j]);
      const float fr = q12(thr);
      const float fi = q12(thi);
      const float sr = __builtin_amdgcn_sinf(fr), cr = __builtin_amdgcn_cosf(fr);
      const float si = __builtin_amdgcn_sinf(fi), ci = __builtin_amdgcn_cosf(fi);
      hr = cr * ci - sr * si;
      hi = cr * si + sr * ci;
      union { unsigned int u; _Float16 h2[2]; } pk;
      pk.h2[0] = (_Float16)hr; pk.h2[1] = (_Float16)hi;
      *(((unsigned int*)(X0 + (size_t)(tt * BB + b) * TWO_K)) + d) = pk.u;
    }
    __syncthreads();  // prefetch landed; all waves done with ebuf[buf]
    buf ^= 1;
  }
  ((float2*)hstate)[b * DD + d] = make_float2(hr, hi);
}

// ---------------- rotation prefix via parallel integer scan ----------------
__global__ __launch_bounds__(256) void k_rot(const float* __restrict__ omega,
                                             float2* __restrict__ C0, float2* __restrict__ D0,
                                             float2* __restrict__ D1, float2* __restrict__ C1last) {
  const int blk = blockIdx.x;               // 0..2047
  const int l = blk >> 10, n = blk & (NN - 1);
  const int tid = threadIdx.x;
  const int lane = tid & 63;
  const int wid = tid >> 6;
  const float om = omega[l * NN + n];

  int pre[4];
  int own = 0;
  const int tb = tid * 4;
#pragma unroll
  for (int j = 0; j < 4; ++j) {
    own += lut_index(om + (float)(tb + j) * 1.618033988749895f);
    pre[j] = own;
  }
  int v = own;
#pragma unroll
  for (int off = 1; off < 64; off <<= 1) {
    int u = __shfl_up(v, off);
    if (lane >= off) v += u;
  }
  __shared__ int wsum[4];
  if (lane == 63) wsum[wid] = v;
  __syncthreads();
  int woff = 0;
#pragma unroll
  for (int w = 0; w < 4; ++w) woff += (w < wid) ? wsum[w] : 0;
  const int excl = woff + v - own;

#pragma unroll
  for (int j = 0; j < 4; ++j) {
    const int t = tb + j;
    const int idx = (excl + pre[j]) & 4095;
    const float s = sinf(0.0015339807878856412f * (float)idx);
    const float c = cosf(0.0015339807878856412f * (float)idx);
    if (l == 0) {
      C0[t * NN + n] = make_float2(c, s);
      D0[t * NN + n] = make_float2(c, -s);
    } else {
      D1[t * NN + n] = make_float2(c, -s);
      if (t == S_LEN - 1) C1last[n] = make_float2(c, s);
    }
  }
}

// ---------------- f16 MFMA GEMM: C = A @ BT^T, optional complex rotation epilogue ----------------
// 1D grid (nblocks % 8 == 0), XCD-swizzled so each XCD owns a contiguous row-block range
// (A-panel exclusive to one L2). nxlog2: log2 of column-block count.
__global__ __launch_bounds__(256, 2) void k_gemm(const _Float16* __restrict__ A,
                                                 const _Float16* __restrict__ BT,
                                                 _Float16* __restrict__ C,
                                                 int M, int N, int K, int nxlog2,
                                                 const float2* __restrict__ rot) {
  __shared__ __align__(16) _Float16 As[128 * 64];
  __shared__ __align__(16) _Float16 Bs[128 * 64];
  const int tid = threadIdx.x;
  const int lane = tid & 63;
  const int wave = tid >> 6;
  const int wm = wave >> 1;
  const int wn = wave & 1;

  const int cpx = gridDim.x >> 3;
  const int bid = blockIdx.x;
  const int swz = (bid & 7) * cpx + (bid >> 3);
  const int bx = swz & ((1 << nxlog2) - 1);
  const int by = swz >> nxlog2;
  const int m0 = by * 128;
  const int n0 = bx * 128;

  const int srow = lane >> 3;               // row within 8-row chunk
  const int schunk = (lane & 7) ^ srow;     // XOR-swizzled source 16B-chunk

  f32x4 acc[4][4] = {};

  for (int kt = 0; kt < K; kt += 64) {
#pragma unroll
    for (int j = 0; j < 4; ++j) {
      const int c = wave * 4 + j;           // chunk 0..15, covers rows c*8..c*8+7
      const int row = c * 8 + srow;
      const _Float16* srcA = A + (size_t)(m0 + row) * K + kt + schunk * 8;
      __builtin_amdgcn_global_load_lds((const __attribute__((address_space(1))) void*)srcA,
                                       (__attribute__((address_space(3))) void*)(As + c * 512), 16, 0, 0);
      const _Float16* srcB = BT + (size_t)(n0 + row) * K + kt + schunk * 8;
      __builtin_amdgcn_global_load_lds((const __attribute__((address_space(1))) void*)srcB,
                                       (__attribute__((address_space(3))) void*)(Bs + c * 512), 16, 0, 0);
    }
    __syncthreads();
#pragma unroll
    for (int ks = 0; ks < 2; ++ks) {
      half8 af[4], bf[4];
#pragma unroll
      for (int mr = 0; mr < 4; ++mr) {
        const int ar = wm * 64 + mr * 16 + (lane & 15);
        const int p = ((ks * 4) + (lane >> 4)) ^ (ar & 7);
        af[mr] = *(const half8*)(As + ar * 64 + p * 8);
      }
#pragma unroll
      for (int nr = 0; nr < 4; ++nr) {
        const int br = wn * 64 + nr * 16 + (lane & 15);
        const int p = ((ks * 4) + (lane >> 4)) ^ (br & 7);
        bf[nr] = *(const half8*)(Bs + br * 64 + p * 8);
      }
#pragma unroll
      for (int mr = 0; mr < 4; ++mr)
#pragma unroll
        for (int nr = 0; nr < 4; ++nr)
          acc[mr][nr] = __builtin_amdgcn_mfma_f32_16x16x32_f16(af[mr], bf[nr], acc[mr][nr], 0, 0, 0);
    }
    __syncthreads();
  }

  const int halfN = N >> 1;
  const int t = by;                          // BM == BB: one row-block == one t
#pragma unroll
  for (int mr = 0; mr < 4; ++mr)
#pragma unroll
    for (int nr = 0; nr < 4; ++nr) {
      const int col = n0 + wn * 64 + nr * 16 + (lane & 15);
      const int rbase = m0 + wm * 64 + mr * 16 + ((lane >> 4) << 2);
      float2 dr = make_float2(1.f, 0.f);
      if (rot) dr = rot[(size_t)t * halfN + (col >> 1)];
#pragma unroll
      for (int j = 0; j < 4; ++j) {
        float v = acc[mr][nr][j];
        if (rot) {
          const float pv = __shfl_xor(v, 1);
          v = (lane & 1) ? (dr.x * v + dr.y * pv) : (dr.x * v - dr.y * pv);
        }
        C[(size_t)(rbase + j) * N + col] = (_Float16)v;
      }
    }
}

// ---------------- prefix-sum over t (in place), then multiply by C0[t] ----------------
// 2 complex/thread, unroll-8 with register double-buffered prefetch (latency cover).
#define SUF 8
__global__ __launch_bounds__(256) void k_scan(_Float16* __restrict__ V,          // [CH*BB, TWO_N]
                                              const float2* __restrict__ C0c,    // [CH, NN]
                                              float2* __restrict__ ZS, int CH, int first) {
  const int gid = blockIdx.x * 256 + threadIdx.x;  // b*(NN/2) + npair
  const int npair = gid & (NN / 2 - 1);
  const int b = gid >> 9;
  const int n = npair * 2;
  float zr0, zi0, zr1, zi1;
  if (first) { zr0 = zi0 = zr1 = zi1 = 0.f; }
  else {
    float4 z = *(const float4*)(ZS + (size_t)b * NN + n);
    zr0 = z.x; zi0 = z.y; zr1 = z.z; zi1 = z.w;
  }
  uint2 vb[SUF], vn[SUF];
  float4 cb[SUF], cn[SUF];
#pragma unroll
  for (int j = 0; j < SUF; ++j) {
    vb[j] = *(const uint2*)(((const unsigned int*)(V + (size_t)(j * BB + b) * TWO_N)) + n);
    cb[j] = *(const float4*)(C0c + (size_t)j * NN + n);
  }
  for (int st = 0; st < CH; st += SUF) {
    const bool more = (st + SUF) < CH;
    if (more) {
#pragma unroll
      for (int j = 0; j < SUF; ++j) {
        vn[j] = *(const uint2*)(((const unsigned int*)(V + (size_t)((st + SUF + j) * BB + b) * TWO_N)) + n);
        cn[j] = *(const float4*)(C0c + (size_t)(st + SUF + j) * NN + n);
      }
    }
#pragma unroll
    for (int j = 0; j < SUF; ++j) {
      union { unsigned int u; _Float16 h2[2]; } a, c;
      a.u = vb[j].x; c.u = vb[j].y;
      zr0 += (float)a.h2[0]; zi0 += (float)a.h2[1];
      zr1 += (float)c.h2[0]; zi1 += (float)c.h2[1];
      const float4 cc = cb[j];
      a.h2[0] = (_Float16)(cc.x * zr0 - cc.y * zi0);
      a.h2[1] = (_Float16)(cc.x * zi0 + cc.y * zr0);
      c.h2[0] = (_Float16)(cc.z * zr1 - cc.w * zi1);
      c.h2[1] = (_Float16)(cc.z * zi1 + cc.w * zr1);
      *(uint2*)(((unsigned int*)(V + (size_t)((st + j) * BB + b) * TWO_N)) + n) = make_uint2(a.u, c.u);
    }
#pragma unroll
    for (int j = 0; j < SUF; ++j) { vb[j] = vn[j]; cb[j] = cn[j]; }
  }
  *(float4*)(ZS + (size_t)b * NN + n) = make_float4(zr0, zi0, zr1, zi1);
}

// ---------------- reduce over t: s1[b, np4] += sum_t U[t,b,np4] ----------------
__global__ __launch_bounds__(256) void k_reduce(const _Float16* __restrict__ U,  // [CH*BB, TWO_N]
                                                float* __restrict__ s1, int CH, int first) {
  const int gid = blockIdx.x * 256 + threadIdx.x;  // b*(TWO_N/4) + g
  const int g = gid & (TWO_N / 4 - 1);
  const int b = gid >> 9;
  const int np = g * 4;
  f32x4 acc;
  if (first) {
#pragma unroll
    for (int j = 0; j < 4; ++j) acc[j] = 0.f;
  } else {
    acc = *(const f32x4*)(s1 + (size_t)b * TWO_N + np);
  }
  half4 vb[SUF], vn[SUF];
#pragma unroll
  for (int j = 0; j < SUF; ++j)
    vb[j] = *(const half4*)(U + (size_t)(j * BB + b) * TWO_N + np);
  for (int st = 0; st < CH; st += SUF) {
    const bool more = (st + SUF) < CH;
    if (more) {
#pragma unroll
      for (int j = 0; j < SUF; ++j)
        vn[j] = *(const half4*)(U + (size_t)((st + SUF + j) * BB + b) * TWO_N + np);
    }
#pragma unroll
    for (int j = 0; j < SUF; ++j) {
#pragma unroll
      for (int q = 0; q < 4; ++q) acc[q] += (float)vb[j][q];
    }
#pragma unroll
    for (int j = 0; j < SUF; ++j) vb[j] = vn[j];
  }
  *(f32x4*)(s1 + (size_t)b * TWO_N + np) = acc;
}

// ---------------- s1c = C1last (*) s1 ----------------
__global__ __launch_bounds__(256) void k_s1c(const float* __restrict__ s1,
                                             const float2* __restrict__ C1last,
                                             float* __restrict__ s1c) {
  const int gid = blockIdx.x * 256 + threadIdx.x;  // b*NN + n
  const int n = gid & (NN - 1);
  const int b = gid >> 10;
  const float sr = s1[b * TWO_N + 2 * n], si = s1[b * TWO_N + 2 * n + 1];
  const float2 c = C1last[n];
  s1c[b * TWO_N + 2 * n]     = c.x * sr - c.y * si;
  s1c[b * TWO_N + 2 * n + 1] = c.x * si + c.y * sr;
}

// ---------------- tail GEMM: one wave per output, A [M,K] f32, BT [N,K] f32 ----------------
__global__ __launch_bounds__(256) void k_tail(const float* __restrict__ A,
                                              const float* __restrict__ BT,
                                              float* __restrict__ C, int M, int N, int K) {
  const int wave = threadIdx.x >> 6;
  const int lane = threadIdx.x & 63;
  const int o = blockIdx.x * 4 + wave;     // output index
  if (o >= M * N) return;
  const int row = o / N;
  const int col = o - row * N;
  const float4* __restrict__ a4 = (const float4*)(A + (size_t)row * K);
  const float4* __restrict__ b4 = (const float4*)(BT + (size_t)col * K);
  float acc = 0.f;
  const int nit = K >> 8;                  // K / (64 lanes * 4)
  for (int it = 0; it < nit; ++it) {
    const float4 av = a4[it * 64 + lane];
    const float4 bv = b4[it * 64 + lane];
    acc = fmaf(av.x, bv.x, acc);
    acc = fmaf(av.y, bv.y, acc);
    acc = fmaf(av.z, bv.z, acc);
    acc = fmaf(av.w, bv.w, acc);
  }
#pragma unroll
  for (int s = 32; s >= 1; s >>= 1) acc += __shfl_xor(acc, s);
  if (lane == 0) C[o] = acc;
}

// ---------------- weight packing ----------------
__global__ __launch_bounds__(256) void k_prep_in(const float* __restrict__ r, const float* __restrict__ im,
                                                 _Float16* __restrict__ dst) {
  const int gid = blockIdx.x * 256 + threadIdx.x;  // k*NN + n
  const int n = gid & (NN - 1);
  const int k = gid >> 10;
  const float rv = r[(size_t)k * NN + n], iv = im[(size_t)k * NN + n];
  const size_t base = (size_t)(2 * n) * TWO_K + 2 * k;
  dst[base] = (_Float16)rv;              dst[base + 1] = (_Float16)(-iv);
  dst[base + TWO_K] = (_Float16)iv;      dst[base + TWO_K + 1] = (_Float16)rv;
}
__global__ __launch_bounds__(256) void k_prep_out(const float* __restrict__ r, const float* __restrict__ im,
                                                  _Float16* __restrict__ dst) {
  const int gid = blockIdx.x * 256 + threadIdx.x;  // n*DD + d
  const int d = gid & (DD - 1);
  const int n = gid >> 8;
  const float rv = r[(size_t)n * DD + d], iv = im[(size_t)n * DD + d];
  const size_t base = (size_t)(2 * d) * TWO_N + 2 * n;
  dst[base] = (_Float16)rv;              dst[base + 1] = (_Float16)(-iv);
  dst[base + TWO_N] = (_Float16)iv;      dst[base + TWO_N + 1] = (_Float16)rv;
}
__global__ __launch_bounds__(256) void k_prep_wout1T(const float* __restrict__ r, const float* __restrict__ im,
                                                     float* __restrict__ dstT) {
  const int gid = blockIdx.x * 256 + threadIdx.x;  // d*NN + n
  const int n = gid & (NN - 1);
  const int d = gid >> 10;
  const float rv = r[(size_t)n * DD + d], iv = im[(size_t)n * DD + d];
  const size_t b0 = (size_t)(2 * d) * TWO_N + 2 * n;
  const size_t b1 = (size_t)(2 * d + 1) * TWO_N + 2 * n;
  dstT[b0] = rv;     dstT[b0 + 1] = -iv;
  dstT[b1] = iv;     dstT[b1 + 1] = rv;
}
__global__ __launch_bounds__(256) void k_prep_finT(const float* __restrict__ pr, const float* __restrict__ pi_,
                                                   float* __restrict__ dstT) {
  const int gid = blockIdx.x * 256 + threadIdx.x;  // s*DD + d
  const int d = gid & (DD - 1);
  const int s = gid >> 8;
  const float a = pr[(size_t)d * 256 + s], b = pi_[(size_t)d * 256 + s];
  dstT[(size_t)s * TWO_K + 2 * d] = a + b;
  dstT[(size_t)s * TWO_K + 2 * d + 1] = a - b;
}

extern "C" void kernel_launch(void* const* d_in, const int* in_sizes, int n_in,
                              void* d_out, int out_size, void* d_ws, size_t ws_size,
                              hipStream_t stream) {
  const int* ids      = (const int*)d_in[0];
  const float* emb    = (const float*)d_in[1];
  const float* win_r  = (const float*)d_in[2];
  const float* win_i  = (const float*)d_in[3];
  const float* wout_r = (const float*)d_in[4];
  const float* wout_i = (const float*)d_in[5];
  const float* omega  = (const float*)d_in[6];
  const float* outp_r = (const float*)d_in[7];
  const float* outp_i = (const float*)d_in[8];

  char* ws = (char*)d_ws;
  size_t off = 0;
  auto alloc = [&](size_t bytes) { void* p = ws + off; off += (bytes + 255) & ~(size_t)255; return p; };

  float2* C0     = (float2*)alloc((size_t)S_LEN * NN * 8);
  float2* D0     = (float2*)alloc((size_t)S_LEN * NN * 8);
  float2* D1     = (float2*)alloc((size_t)S_LEN * NN * 8);
  float2* C1last = (float2*)alloc((size_t)NN * 8);
  float2* ZS     = (float2*)alloc((size_t)BB * NN * 8);
  float* hstate  = (float*)alloc((size_t)BB * DD * 2 * 4);
  float* s1      = (float*)alloc((size_t)BB * TWO_N * 4);
  float* s1c     = (float*)alloc((size_t)BB * TWO_N * 4);
  float* xt      = (float*)alloc((size_t)BB * TWO_K * 4);
  _Float16* BTin0  = (_Float16*)alloc((size_t)TWO_N * TWO_K * 2);
  _Float16* BTout0 = (_Float16*)alloc((size_t)TWO_K * TWO_N * 2);
  _Float16* BTin1  = (_Float16*)alloc((size_t)TWO_N * TWO_K * 2);
  float* Wout1T = (float*)alloc((size_t)TWO_K * TWO_N * 4);
  float* WfinT  = (float*)alloc((size_t)256 * TWO_K * 4);
  const size_t fixed = off;

  // per-chunk buffers: X0 [CH*BB, TWO_K] f16, VB [CH*BB, TWO_N] f16; Yc aliases X0
  int CH = 1024;
  while (CH > 32) {
    size_t need = fixed + (size_t)CH * BB * 2 * (TWO_K + TWO_N) + 2 * 256;
    if (need <= ws_size) break;
    CH >>= 1;
  }
  _Float16* X0 = (_Float16*)alloc((size_t)CH * BB * TWO_K * 2);
  _Float16* VB = (_Float16*)alloc((size_t)CH * BB * TWO_N * 2);
  _Float16* Yc = X0;

  k_rot<<<2 * NN, 256, 0, stream>>>(omega, C0, D0, D1, C1last);
  k_prep_in<<<DD * NN / 256, 256, 0, stream>>>(win_r, win_i, BTin0);
  k_prep_in<<<DD * NN / 256, 256, 0, stream>>>(win_r + (size_t)DD * NN, win_i + (size_t)DD * NN, BTin1);
  k_prep_out<<<NN * DD / 256, 256, 0, stream>>>(wout_r, wout_i, BTout0);
  k_prep_wout1T<<<NN * DD / 256, 256, 0, stream>>>(wout_r + (size_t)NN * DD, wout_i + (size_t)NN * DD, Wout1T);
  k_prep_finT<<<DD * 256 / 256, 256, 0, stream>>>(outp_r, outp_i, WfinT);

  const int nchunks = S_LEN / CH;
  for (int c = 0; c < nchunks; ++c) {
    const int t0 = c * CH;
    const int M = CH * BB;
    k_h<<<BB, 256, 0, stream>>>(ids, emb, hstate, X0, t0, CH);
    const int nb1 = (TWO_N / 128) * (M / 128);   // 16 * (M/128), % 8 == 0
    k_gemm<<<nb1, 256, 0, stream>>>(X0, BTin0, VB, M, TWO_N, TWO_K, 4, D0 + (size_t)t0 * NN);
    k_scan<<<BB * (NN / 2) / 256, 256, 0, stream>>>(VB, C0 + (size_t)t0 * NN, ZS, CH, c == 0);
    const int nb2 = (TWO_K / 128) * (M / 128);   // 4 * (M/128), % 8 == 0
    k_gemm<<<nb2, 256, 0, stream>>>(VB, BTout0, Yc, M, TWO_K, TWO_N, 2, nullptr);
    k_gemm<<<nb1, 256, 0, stream>>>(Yc, BTin1, VB, M, TWO_N, TWO_K, 4, D1 + (size_t)t0 * NN);
    k_reduce<<<BB * (TWO_N / 4) / 256, 256, 0, stream>>>(VB, s1, CH, c == 0);
  }

  k_s1c<<<BB * NN / 256, 256, 0, stream>>>(s1, C1last, s1c);
  // xt[128, 512] = s1c[128, 2048] @ Wout1 (via Wout1T [512, 2048])
  k_tail<<<BB * TWO_K / 4, 256, 0, stream>>>(s1c, Wout1T, xt, BB, TWO_K, TWO_N);
  // out[128, 256] = xt[128, 512] @ Wfin (via WfinT [256, 512])
  k_tail<<<BB * 256 / 4, 256, 0, stream>>>(xt, WfinT, (float*)d_out, BB, 256, TWO_K);
}